// Round 2
// baseline (1103.531 us; speedup 1.0000x reference)
//
#include <hip/hip_runtime.h>
#include <math.h>

#define N_NODE 40000
#define EMB 100
#define BB 512
#define LL 50
#define NI 50
#define EDG 800000

// ---------------- CSR build ----------------
__global__ void khist(const int* __restrict__ rows, int* __restrict__ counts) {
  int e = blockIdx.x * 256 + threadIdx.x;
  atomicAdd(&counts[rows[e]], 1);
}

__global__ void kscan(const int* __restrict__ counts, int* __restrict__ starts,
                      int* __restrict__ cursor, int n) {
  int lane = threadIdx.x;  // 64 threads, 1 block
  int carry = 0;
  for (int base = 0; base < n; base += 64) {
    int i = base + lane;
    int v = (i < n) ? counts[i] : 0;
    int x = v;
    #pragma unroll
    for (int off = 1; off < 64; off <<= 1) {
      int t = __shfl_up(x, off, 64);
      if (lane >= off) x += t;
    }
    int excl = carry + x - v;
    if (i < n) { starts[i] = excl; cursor[i] = excl; }
    carry += __shfl(x, 63, 64);
  }
}

__global__ void kfill(const int* __restrict__ rows, const int* __restrict__ cols,
                      const float* __restrict__ vals, int* __restrict__ cursor,
                      int* __restrict__ colS, float* __restrict__ valS) {
  int e = blockIdx.x * 256 + threadIdx.x;
  int r = rows[e];
  int p = atomicAdd(&cursor[r], 1);
  colS[p] = cols[e];
  valS[p] = vals[e];
}

// ---------------- gather SpMM (wave per row) ----------------
__global__ void kspmm(const int* __restrict__ starts, const int* __restrict__ counts,
                      const int* __restrict__ colS, const float* __restrict__ valS,
                      const float* __restrict__ x, float* __restrict__ out) {
  int row = blockIdx.x * 4 + (threadIdx.x >> 6);
  int lane = threadIdx.x & 63;
  int s = starts[row], cnt = counts[row];
  int d0 = lane, d1 = lane + 64;
  bool h1 = d1 < EMB;
  float a0 = 0.f, a1 = 0.f;
  for (int t = 0; t < cnt; ++t) {
    int c = colS[s + t];
    float v = valS[s + t];
    const float* xr = x + (size_t)c * EMB;
    a0 += v * xr[d0];
    if (h1) a1 += v * xr[d1];
  }
  out[(size_t)row * EMB + d0] = a0;
  if (h1) out[(size_t)row * EMB + d1] = a1;
}

// ---------------- l2norm-combine (item conv epilogue) ----------------
__global__ void kcomb(const float* __restrict__ x0, const float* __restrict__ x1,
                      const float* __restrict__ x2, const float* __restrict__ bI,
                      float* __restrict__ emb) {
  int n = blockIdx.x * 4 + (threadIdx.x >> 6);
  int lane = threadIdx.x & 63;
  int d0 = lane, d1 = lane + 64;
  bool h1 = d1 < EMB;
  size_t base = (size_t)n * EMB;
  float v00 = x0[base + d0], v01 = h1 ? x0[base + d1] : 0.f;
  float v10 = x1[base + d0], v11 = h1 ? x1[base + d1] : 0.f;
  float v20 = x2[base + d0], v21 = h1 ? x2[base + d1] : 0.f;
  float q0 = v00 * v00 + v01 * v01;
  float q1 = v10 * v10 + v11 * v11;
  float q2 = v20 * v20 + v21 * v21;
  #pragma unroll
  for (int off = 32; off; off >>= 1) {
    q0 += __shfl_xor(q0, off);
    q1 += __shfl_xor(q1, off);
    q2 += __shfl_xor(q2, off);
  }
  float r0 = 1.f / fmaxf(sqrtf(q0), 1e-12f);
  float r1 = 1.f / fmaxf(sqrtf(q1), 1e-12f);
  float r2 = 1.f / fmaxf(sqrtf(q2), 1e-12f);
  float b0 = bI[0], b1 = bI[1], b2 = bI[2];
  emb[base + d0] = b0 * v00 * r0 + b1 * v10 * r1 + b2 * v20 * r2;
  if (h1) emb[base + d1] = b0 * v01 * r0 + b1 * v11 * r1 + b2 * v21 * r2;
}

// ---------------- GAT (block per batch, wave per row) ----------------
__global__ __launch_bounds__(256) void kgat(
    const float* __restrict__ emb, const int* __restrict__ items,
    const int* __restrict__ adj,
    const float* __restrict__ a0p, const float* __restrict__ a1p,
    const float* __restrict__ a2p, const float* __restrict__ a3p,
    float* __restrict__ hgat) {
  __shared__ float hl[NI * 101 + 80];
  __shared__ float as[4 * 100];
  __shared__ float al[4 * 64];
  int b = blockIdx.x;
  int tid = threadIdx.x;
  for (int idx = tid; idx < 400; idx += 256) {
    int k = idx / 100, d = idx % 100;
    const float* ap = (k == 0) ? a0p : (k == 1) ? a1p : (k == 2) ? a2p : a3p;
    as[idx] = ap[d];
  }
  for (int idx = tid; idx < NI * 100; idx += 256) {
    int i = idx / 100, d = idx % 100;
    int node = items[b * NI + i];
    hl[i * 101 + d] = (node == 0) ? 0.f : emb[(size_t)(node - 1) * EMB + d];
  }
  __syncthreads();
  int w = tid >> 6, lane = tid & 63;
  for (int i = w; i < NI; i += 4) {
    float s0 = 0, s1 = 0, s2 = 0, s3 = 0;
    if (lane < NI) {
      const float* hi = &hl[i * 101];
      const float* hj = &hl[lane * 101];
      for (int d = 0; d < 100; ++d) {
        float p = hi[d] * hj[d];
        s0 += p * as[d];
        s1 += p * as[100 + d];
        s2 += p * as[200 + d];
        s3 += p * as[300 + d];
      }
    }
    float e = -INFINITY;
    if (lane < NI) {
      int av = adj[(size_t)b * (NI * NI) + i * NI + lane];
      float sv = (av == 1) ? s0 : (av == 2) ? s1 : (av == 3) ? s2 : s3;
      sv = (sv >= 0.f) ? sv : 0.2f * sv;
      e = (av == 0) ? -9e15f : sv;
    }
    float m = e;
    #pragma unroll
    for (int off = 32; off; off >>= 1) m = fmaxf(m, __shfl_xor(m, off));
    float p = (lane < NI) ? expf(e - m) : 0.f;
    float ssum = p;
    #pragma unroll
    for (int off = 32; off; off >>= 1) ssum += __shfl_xor(ssum, off);
    al[w * 64 + lane] = p / ssum;
    int d0 = lane, d1 = lane + 64;
    float acc0 = 0.f, acc1 = 0.f;
    for (int j = 0; j < NI; ++j) {
      float a = al[w * 64 + j];
      acc0 += a * hl[j * 101 + d0];
      acc1 += a * hl[j * 101 + d1];  // padded array: safe garbage for d1>=100
    }
    size_t ob = ((size_t)b * NI + i) * EMB;
    hgat[ob + d0] = acc0;
    if (d1 < EMB) hgat[ob + d1] = acc1;
  }
}

// ---------------- get_seq mix ----------------
__global__ void kseq(const float* __restrict__ emb, const int* __restrict__ rev,
                     const int* __restrict__ alias, const float* __restrict__ hgat,
                     float* __restrict__ hseq) {
  int idx = blockIdx.x * 256 + threadIdx.x;  // 2,560,000 exact
  int b = idx / 5000, r = idx % 5000, l = r / 100, d = r % 100;
  int node = rev[b * LL + l];
  float sh = (node == 0) ? 0.f : emb[(size_t)(node - 1) * EMB + d];
  int a = alias[b * LL + l];
  float shh = hgat[((size_t)b * NI + a) * EMB + d];
  hseq[idx] = 0.2f * sh + 0.8f * shh;
}

// ---------------- weight prep: transposes + pos@W1a ----------------
__global__ void kprep_t(const float* __restrict__ w1W, const float* __restrict__ g1W,
                        const float* __restrict__ g2W, float* __restrict__ w1t2,
                        float* __restrict__ g1t, float* __restrict__ g2t) {
  int idx = blockIdx.x * 256 + threadIdx.x;
  if (idx >= 10000) return;
  int c = idx / 100, o = idx % 100;
  w1t2[c * 100 + o] = w1W[o * 200 + 100 + c];
  g1t[c * 100 + o] = g1W[o * 100 + c];
  g2t[c * 100 + o] = g2W[o * 100 + c];
}

__global__ void kprep_pos(const float* __restrict__ posE, const float* __restrict__ w1W,
                          const float* __restrict__ w1b, float* __restrict__ posW) {
  int idx = blockIdx.x * 256 + threadIdx.x;
  if (idx >= 5000) return;
  int l = idx / 100, o = idx % 100;
  float acc = w1b[o];
  for (int c = 0; c < 100; ++c) acc += posE[l * 100 + c] * w1W[o * 200 + c];
  posW[idx] = acc;
}

// ---------------- soft attention (block per batch) ----------------
__global__ __launch_bounds__(256) void ksoft(
    const float* __restrict__ hseqG, const float* __restrict__ slenp,
    const int* __restrict__ maskp,
    const float* __restrict__ posW, const float* __restrict__ w1t2,
    const float* __restrict__ glu1t, const float* __restrict__ glu1b,
    const float* __restrict__ glu2t, const float* __restrict__ w2,
    float* __restrict__ sel) {
  __shared__ float hq[LL * 101];
  __shared__ float nh[LL * 100];
  __shared__ float hs_s[100];
  __shared__ float g_s[100];
  __shared__ float beta_s[LL];
  int b = blockIdx.x, tid = threadIdx.x;
  for (int idx = tid; idx < LL * 100; idx += 256) {
    int l = idx / 100, d = idx % 100;
    hq[l * 101 + d] = hseqG[((size_t)b * LL + l) * 100 + d];
  }
  __syncthreads();
  if (tid < 100) {
    float s = 0.f;
    for (int l = 0; l < LL; ++l) s += hq[l * 101 + tid];
    hs_s[tid] = s / slenp[b];
  }
  __syncthreads();
  if (tid < 100) {
    float acc = 0.f;
    for (int c = 0; c < 100; ++c) acc += hs_s[c] * glu2t[c * 100 + tid];
    g_s[tid] = acc;
  }
  for (int idx = tid; idx < LL * 100; idx += 256) {
    int l = idx / 100, o = idx % 100;
    float acc = posW[idx];
    for (int c = 0; c < 100; ++c) acc += hq[l * 101 + c] * w1t2[c * 100 + o];
    nh[idx] = tanhf(acc);
  }
  __syncthreads();
  float vals[20];
  int cnt = 0;
  for (int idx = tid; idx < LL * 100; idx += 256) {
    int l = idx / 100, o = idx % 100;
    float acc = g_s[o] + glu1b[o];
    for (int c = 0; c < 100; ++c) acc += nh[l * 100 + c] * glu1t[c * 100 + o];
    float sg = 1.f / (1.f + expf(-acc));
    vals[cnt++] = sg * w2[o];
  }
  __syncthreads();
  cnt = 0;
  for (int idx = tid; idx < LL * 100; idx += 256) nh[idx] = vals[cnt++];
  __syncthreads();
  int w = tid >> 6, lane = tid & 63;
  for (int l = w; l < LL; l += 4) {
    float s = nh[l * 100 + lane];
    if (lane + 64 < 100) s += nh[l * 100 + lane + 64];
    #pragma unroll
    for (int off = 32; off; off >>= 1) s += __shfl_xor(s, off);
    if (lane == 0) beta_s[l] = s * (float)maskp[b * LL + l];
  }
  __syncthreads();
  if (tid < 100) {
    float acc = 0.f;
    for (int l = 0; l < LL; ++l) acc += beta_s[l] * hq[l * 101 + tid];
    sel[(size_t)b * 100 + tid] = acc;
  }
}

// ---------------- session conv: dense [512,512] @ [512,100] ----------------
__global__ void ksess(const float* __restrict__ adjS, const float* __restrict__ x,
                      float* __restrict__ out) {
  int b = blockIdx.x, d = threadIdx.x;
  if (d >= 100) return;
  const float* ar = adjS + (size_t)b * BB;
  float a0 = 0.f, a1 = 0.f, a2 = 0.f, a3 = 0.f;
  for (int j = 0; j < BB; j += 4) {
    a0 += ar[j]     * x[(j)     * 100 + d];
    a1 += ar[j + 1] * x[(j + 1) * 100 + d];
    a2 += ar[j + 2] * x[(j + 2) * 100 + d];
    a3 += ar[j + 3] * x[(j + 3) * 100 + d];
  }
  out[(size_t)b * 100 + d] = (a0 + a1) + (a2 + a3);
}

__global__ void ksesscomb(const float* __restrict__ x0, const float* __restrict__ x1,
                          const float* __restrict__ x2, const float* __restrict__ aS,
                          float* __restrict__ out) {
  int b = blockIdx.x * 4 + (threadIdx.x >> 6);
  int lane = threadIdx.x & 63;
  int d0 = lane, d1 = lane + 64;
  bool h1 = d1 < EMB;
  size_t base = (size_t)b * EMB;
  float v00 = x0[base + d0], v01 = h1 ? x0[base + d1] : 0.f;
  float v10 = x1[base + d0], v11 = h1 ? x1[base + d1] : 0.f;
  float v20 = x2[base + d0], v21 = h1 ? x2[base + d1] : 0.f;
  float q0 = v00 * v00 + v01 * v01;
  float q1 = v10 * v10 + v11 * v11;
  float q2 = v20 * v20 + v21 * v21;
  #pragma unroll
  for (int off = 32; off; off >>= 1) {
    q0 += __shfl_xor(q0, off);
    q1 += __shfl_xor(q1, off);
    q2 += __shfl_xor(q2, off);
  }
  float r0 = 1.f / fmaxf(sqrtf(q0), 1e-12f);
  float r1 = 1.f / fmaxf(sqrtf(q1), 1e-12f);
  float r2 = 1.f / fmaxf(sqrtf(q2), 1e-12f);
  float b0 = aS[0], b1 = aS[1], b2 = aS[2];
  // seq_h = sel1+sel2 = 2 * session_conv output
  out[base + d0] = 2.f * (b0 * v00 * r0 + b1 * v10 * r1 + b2 * v20 * r2);
  if (h1) out[base + d1] = 2.f * (b0 * v01 * r0 + b1 * v11 * r1 + b2 * v21 * r2);
}

// ---------------- scores GEMM: [512,100] x [40000,100]^T -> f32 out ----------------
__global__ __launch_bounds__(256) void kscores(const float* __restrict__ seqh,
                                               const float* __restrict__ emb,
                                               float* __restrict__ outS) {
  __shared__ float Sl[100 * 68];
  __shared__ float Gl[100 * 68];
  int n0 = blockIdx.x * 64, b0 = blockIdx.y * 64;
  int tid = threadIdx.x;
  for (int idx = tid; idx < 6400; idx += 256) {
    int r = idx / 100, c = idx % 100;
    Sl[c * 68 + r] = seqh[(size_t)(b0 + r) * 100 + c];
    Gl[c * 68 + r] = 2.f * emb[(size_t)(n0 + r) * 100 + c];  // embeddings = 2*emb_gnn
  }
  __syncthreads();
  int tx = tid & 15, ty = tid >> 4;
  float acc[4][4];
  #pragma unroll
  for (int i = 0; i < 4; i++)
    #pragma unroll
    for (int j = 0; j < 4; j++) acc[i][j] = 0.f;
  for (int c = 0; c < 100; ++c) {
    float4 sv = *(const float4*)&Sl[c * 68 + ty * 4];
    float4 gv = *(const float4*)&Gl[c * 68 + tx * 4];
    float ss[4] = {sv.x, sv.y, sv.z, sv.w};
    float gg[4] = {gv.x, gv.y, gv.z, gv.w};
    #pragma unroll
    for (int i = 0; i < 4; i++)
      #pragma unroll
      for (int j = 0; j < 4; j++) acc[i][j] += ss[i] * gg[j];
  }
  #pragma unroll
  for (int i = 0; i < 4; i++) {
    int b = b0 + ty * 4 + i;
    size_t base = (size_t)b * N_NODE + n0 + tx * 4;
    // outS is (d_out + 2 floats): byte offset 8 + 16k -> 8B aligned; use float2
    float2 p0 = make_float2(acc[i][0], acc[i][1]);
    float2 p1 = make_float2(acc[i][2], acc[i][3]);
    *(float2*)&outS[base] = p0;
    *(float2*)&outS[base + 2] = p1;
  }
}

// ---------------- per-row logsumexp + target score ----------------
__global__ __launch_bounds__(256) void klse(const float* __restrict__ outS,
                                            const int* __restrict__ tar,
                                            float* __restrict__ part) {
  __shared__ float ms[256], ss[256];
  int b = blockIdx.x, tid = threadIdx.x;
  const float2* sp = (const float2*)(outS + (size_t)b * N_NODE);
  float m = -INFINITY, s = 0.f;
  for (int i = tid; i < N_NODE / 2; i += 256) {
    float2 v = sp[i];
    float mx = fmaxf(v.x, v.y);
    float add = expf(v.x - mx) + expf(v.y - mx);
    if (mx > m) { s = s * expf(m - mx) + add; m = mx; }
    else s += add * expf(mx - m);
  }
  ms[tid] = m; ss[tid] = s;
  __syncthreads();
  for (int st = 128; st; st >>= 1) {
    if (tid < st) {
      float m2 = ms[tid + st], s2 = ss[tid + st];
      float M = fmaxf(ms[tid], m2);
      ss[tid] = ss[tid] * expf(ms[tid] - M) + s2 * expf(m2 - M);
      ms[tid] = M;
    }
    __syncthreads();
  }
  if (tid == 0) {
    float tsc = outS[(size_t)b * N_NODE + tar[b]];
    part[b] = tsc - (ms[0] + logf(ss[0]));
  }
}

__global__ void kfinal(const float* __restrict__ part, float* __restrict__ out) {
  __shared__ float red[256];
  int tid = threadIdx.x;
  red[tid] = part[tid] + part[tid + 256];
  __syncthreads();
  for (int st = 128; st; st >>= 1) {
    if (tid < st) red[tid] += red[tid + st];
    __syncthreads();
  }
  if (tid == 0) {
    out[0] = 0.f;                        // con_loss
    out[1] = -red[0] / (float)BB;        // loss
  }
}

extern "C" void kernel_launch(void* const* d_in, const int* in_sizes, int n_in,
                              void* d_out, int out_size, void* d_ws, size_t ws_size,
                              hipStream_t stream) {
  const int* tar    = (const int*)d_in[0];
  const int* rev    = (const int*)d_in[1];
  const int* maskp  = (const int*)d_in[2];
  const float* slen = (const float*)d_in[3];
  const float* sadj = (const float*)d_in[4];
  const int* items  = (const int*)d_in[6];
  const int* adjp   = (const int*)d_in[7];
  const int* alias  = (const int*)d_in[8];
  const int* grows  = (const int*)d_in[9];
  const int* gcols  = (const int*)d_in[10];
  const float* gvals = (const float*)d_in[11];
  const float* nemb = (const float*)d_in[12];
  const float* bI   = (const float*)d_in[13];
  const float* aS   = (const float*)d_in[14];
  const float* a0p  = (const float*)d_in[15];
  const float* a1p  = (const float*)d_in[16];
  const float* a2p  = (const float*)d_in[17];
  const float* a3p  = (const float*)d_in[18];
  const float* w1W  = (const float*)d_in[19];
  const float* w1b  = (const float*)d_in[20];
  const float* w2p  = (const float*)d_in[21];
  const float* g1W  = (const float*)d_in[22];
  const float* g1b  = (const float*)d_in[23];
  const float* g2W  = (const float*)d_in[24];
  const float* posE = (const float*)d_in[25];

  float* W = (float*)d_ws;
  size_t o = 0;
  float* emb_gnn = W + o; o += (size_t)N_NODE * EMB;   // 4,000,000
  float* x1      = W + o; o += (size_t)N_NODE * EMB;   // reused: hgat
  float* x2      = W + o; o += (size_t)N_NODE * EMB;   // reused: hseq
  float* sel     = W + o; o += (size_t)BB * EMB;
  float* y1      = W + o; o += (size_t)BB * EMB;
  float* y2      = W + o; o += (size_t)BB * EMB;
  float* seqh    = W + o; o += (size_t)BB * EMB;
  float* posW    = W + o; o += 5120;
  float* w1t2    = W + o; o += 10000;
  float* glu1t   = W + o; o += 10000;
  float* glu2t   = W + o; o += 10000;
  float* valS    = W + o; o += EDG;
  float* part    = W + o; o += 512;
  int* colS   = (int*)(W + o); o += EDG;
  int* counts = (int*)(W + o); o += N_NODE;
  int* starts = (int*)(W + o); o += N_NODE;
  int* cursor = (int*)(W + o); o += N_NODE;
  // hgat/hseq alias x1/x2 (dead after kcomb); 2.56e6 <= 4e6 each
  float* hgat = x1;
  float* hseq = x2;

  float* outF = (float*)d_out;
  float* outScores = outF + 2;

  hipMemsetAsync(counts, 0, N_NODE * sizeof(int), stream);
  khist<<<EDG / 256, 256, 0, stream>>>(grows, counts);
  kscan<<<1, 64, 0, stream>>>(counts, starts, cursor, N_NODE);
  kfill<<<EDG / 256, 256, 0, stream>>>(grows, gcols, gvals, cursor, colS, valS);
  kspmm<<<N_NODE / 4, 256, 0, stream>>>(starts, counts, colS, valS, nemb, x1);
  kspmm<<<N_NODE / 4, 256, 0, stream>>>(starts, counts, colS, valS, x1, x2);
  kcomb<<<N_NODE / 4, 256, 0, stream>>>(nemb, x1, x2, bI, emb_gnn);
  kgat<<<BB, 256, 0, stream>>>(emb_gnn, items, adjp, a0p, a1p, a2p, a3p, hgat);
  kseq<<<(BB * LL * EMB) / 256, 256, 0, stream>>>(emb_gnn, rev, alias, hgat, hseq);
  kprep_t<<<40, 256, 0, stream>>>(w1W, g1W, g2W, w1t2, glu1t, glu2t);
  kprep_pos<<<20, 256, 0, stream>>>(posE, w1W, w1b, posW);
  ksoft<<<BB, 256, 0, stream>>>(hseq, slen, maskp, posW, w1t2, glu1t, g1b, glu2t, w2p, sel);
  ksess<<<BB, 128, 0, stream>>>(sadj, sel, y1);
  ksess<<<BB, 128, 0, stream>>>(sadj, y1, y2);
  ksesscomb<<<BB / 4, 256, 0, stream>>>(sel, y1, y2, aS, seqh);
  kscores<<<dim3(N_NODE / 64, BB / 64), 256, 0, stream>>>(seqh, emb_gnn, outScores);
  klse<<<BB, 256, 0, stream>>>(outScores, tar, part);
  kfinal<<<1, 256, 0, stream>>>(part, outF);
}

// Round 3
// 809.411 us; speedup vs baseline: 1.3634x; 1.3634x over previous
//
#include <hip/hip_runtime.h>
#include <math.h>

#define N_NODE 40000
#define EMB 100
#define BB 512
#define LL 50
#define NI 50
#define EDG 800000
#define SCAN_BLOCKS 157  // ceil(40000/256)

// ---------------- CSR build ----------------
__global__ void khist(const int* __restrict__ rows, int* __restrict__ counts) {
  int e = blockIdx.x * 256 + threadIdx.x;
  atomicAdd(&counts[rows[e]], 1);
}

// block-local exclusive scan (256 elems/block) + block sums
__global__ __launch_bounds__(256) void kscan1(const int* __restrict__ counts,
                                              int* __restrict__ scanout,
                                              int* __restrict__ blocksums, int n) {
  __shared__ int wsum[4];
  int tid = threadIdx.x;
  int i = blockIdx.x * 256 + tid;
  int v = (i < n) ? counts[i] : 0;
  int x = v;
  #pragma unroll
  for (int off = 1; off < 64; off <<= 1) {
    int t = __shfl_up(x, off, 64);
    if ((tid & 63) >= off) x += t;
  }
  int w = tid >> 6, lane = tid & 63;
  if (lane == 63) wsum[w] = x;
  __syncthreads();
  int woff = 0;
  #pragma unroll
  for (int k = 0; k < 4; ++k) woff += (k < w) ? wsum[k] : 0;
  int incl = x + woff;
  if (i < n) scanout[i] = incl - v;  // block-local exclusive
  if (tid == 255) blocksums[blockIdx.x] = incl;
}

// scan the block sums (one block, 256 threads >= 157)
__global__ __launch_bounds__(256) void kscan2(int* __restrict__ blocksums, int nb) {
  __shared__ int wsum[4];
  int tid = threadIdx.x;
  int v = (tid < nb) ? blocksums[tid] : 0;
  int x = v;
  #pragma unroll
  for (int off = 1; off < 64; off <<= 1) {
    int t = __shfl_up(x, off, 64);
    if ((tid & 63) >= off) x += t;
  }
  int w = tid >> 6, lane = tid & 63;
  if (lane == 63) wsum[w] = x;
  __syncthreads();
  int woff = 0;
  #pragma unroll
  for (int k = 0; k < 4; ++k) woff += (k < w) ? wsum[k] : 0;
  if (tid < nb) blocksums[tid] = x + woff - v;  // exclusive
}

// add block offsets, produce starts + cursor
__global__ __launch_bounds__(256) void kscan3(const int* __restrict__ scanout,
                                              const int* __restrict__ blocksums,
                                              int* __restrict__ starts,
                                              int* __restrict__ cursor, int n) {
  int i = blockIdx.x * 256 + threadIdx.x;
  if (i < n) {
    int s = scanout[i] + blocksums[blockIdx.x];
    starts[i] = s;
    cursor[i] = s;
  }
}

__global__ void kfill(const int* __restrict__ rows, const int* __restrict__ cols,
                      const float* __restrict__ vals, int* __restrict__ cursor,
                      int* __restrict__ colS, float* __restrict__ valS) {
  int e = blockIdx.x * 256 + threadIdx.x;
  int r = rows[e];
  int p = atomicAdd(&cursor[r], 1);
  colS[p] = cols[e];
  valS[p] = vals[e];
}

// ---------------- gather SpMM (wave per row) ----------------
__global__ void kspmm(const int* __restrict__ starts, const int* __restrict__ counts,
                      const int* __restrict__ colS, const float* __restrict__ valS,
                      const float* __restrict__ x, float* __restrict__ out) {
  int row = blockIdx.x * 4 + (threadIdx.x >> 6);
  int lane = threadIdx.x & 63;
  int s = starts[row], cnt = counts[row];
  int d0 = lane, d1 = lane + 64;
  bool h1 = d1 < EMB;
  float a0 = 0.f, a1 = 0.f;
  for (int t = 0; t < cnt; ++t) {
    int c = colS[s + t];
    float v = valS[s + t];
    const float* xr = x + (size_t)c * EMB;
    a0 += v * xr[d0];
    if (h1) a1 += v * xr[d1];
  }
  out[(size_t)row * EMB + d0] = a0;
  if (h1) out[(size_t)row * EMB + d1] = a1;
}

// ---------------- l2norm-combine (item conv epilogue) ----------------
__global__ void kcomb(const float* __restrict__ x0, const float* __restrict__ x1,
                      const float* __restrict__ x2, const float* __restrict__ bI,
                      float* __restrict__ emb) {
  int n = blockIdx.x * 4 + (threadIdx.x >> 6);
  int lane = threadIdx.x & 63;
  int d0 = lane, d1 = lane + 64;
  bool h1 = d1 < EMB;
  size_t base = (size_t)n * EMB;
  float v00 = x0[base + d0], v01 = h1 ? x0[base + d1] : 0.f;
  float v10 = x1[base + d0], v11 = h1 ? x1[base + d1] : 0.f;
  float v20 = x2[base + d0], v21 = h1 ? x2[base + d1] : 0.f;
  float q0 = v00 * v00 + v01 * v01;
  float q1 = v10 * v10 + v11 * v11;
  float q2 = v20 * v20 + v21 * v21;
  #pragma unroll
  for (int off = 32; off; off >>= 1) {
    q0 += __shfl_xor(q0, off);
    q1 += __shfl_xor(q1, off);
    q2 += __shfl_xor(q2, off);
  }
  float r0 = 1.f / fmaxf(sqrtf(q0), 1e-12f);
  float r1 = 1.f / fmaxf(sqrtf(q1), 1e-12f);
  float r2 = 1.f / fmaxf(sqrtf(q2), 1e-12f);
  float b0 = bI[0], b1 = bI[1], b2 = bI[2];
  emb[base + d0] = b0 * v00 * r0 + b1 * v10 * r1 + b2 * v20 * r2;
  if (h1) emb[base + d1] = b0 * v01 * r0 + b1 * v11 * r1 + b2 * v21 * r2;
}

// ---------------- GAT (block per batch, wave per row) ----------------
__global__ __launch_bounds__(256) void kgat(
    const float* __restrict__ emb, const int* __restrict__ items,
    const int* __restrict__ adj,
    const float* __restrict__ a0p, const float* __restrict__ a1p,
    const float* __restrict__ a2p, const float* __restrict__ a3p,
    float* __restrict__ hgat) {
  __shared__ float hl[NI * 101 + 80];
  __shared__ float as[4 * 100];
  __shared__ float al[4 * 64];
  int b = blockIdx.x;
  int tid = threadIdx.x;
  for (int idx = tid; idx < 400; idx += 256) {
    int k = idx / 100, d = idx % 100;
    const float* ap = (k == 0) ? a0p : (k == 1) ? a1p : (k == 2) ? a2p : a3p;
    as[idx] = ap[d];
  }
  for (int idx = tid; idx < NI * 100; idx += 256) {
    int i = idx / 100, d = idx % 100;
    int node = items[b * NI + i];
    hl[i * 101 + d] = (node == 0) ? 0.f : emb[(size_t)(node - 1) * EMB + d];
  }
  __syncthreads();
  int w = tid >> 6, lane = tid & 63;
  for (int i = w; i < NI; i += 4) {
    float s0 = 0, s1 = 0, s2 = 0, s3 = 0;
    if (lane < NI) {
      const float* hi = &hl[i * 101];
      const float* hj = &hl[lane * 101];
      for (int d = 0; d < 100; ++d) {
        float p = hi[d] * hj[d];
        s0 += p * as[d];
        s1 += p * as[100 + d];
        s2 += p * as[200 + d];
        s3 += p * as[300 + d];
      }
    }
    float e = -INFINITY;
    if (lane < NI) {
      int av = adj[(size_t)b * (NI * NI) + i * NI + lane];
      float sv = (av == 1) ? s0 : (av == 2) ? s1 : (av == 3) ? s2 : s3;
      sv = (sv >= 0.f) ? sv : 0.2f * sv;
      e = (av == 0) ? -9e15f : sv;
    }
    float m = e;
    #pragma unroll
    for (int off = 32; off; off >>= 1) m = fmaxf(m, __shfl_xor(m, off));
    float p = (lane < NI) ? expf(e - m) : 0.f;
    float ssum = p;
    #pragma unroll
    for (int off = 32; off; off >>= 1) ssum += __shfl_xor(ssum, off);
    al[w * 64 + lane] = p / ssum;
    int d0 = lane, d1 = lane + 64;
    float acc0 = 0.f, acc1 = 0.f;
    for (int j = 0; j < NI; ++j) {
      float a = al[w * 64 + j];
      acc0 += a * hl[j * 101 + d0];
      acc1 += a * hl[j * 101 + d1];  // padded array: safe garbage for d1>=100
    }
    size_t ob = ((size_t)b * NI + i) * EMB;
    hgat[ob + d0] = acc0;
    if (d1 < EMB) hgat[ob + d1] = acc1;
  }
}

// ---------------- get_seq mix ----------------
__global__ void kseq(const float* __restrict__ emb, const int* __restrict__ rev,
                     const int* __restrict__ alias, const float* __restrict__ hgat,
                     float* __restrict__ hseq) {
  int idx = blockIdx.x * 256 + threadIdx.x;  // 2,560,000 exact
  int b = idx / 5000, r = idx % 5000, l = r / 100, d = r % 100;
  int node = rev[b * LL + l];
  float sh = (node == 0) ? 0.f : emb[(size_t)(node - 1) * EMB + d];
  int a = alias[b * LL + l];
  float shh = hgat[((size_t)b * NI + a) * EMB + d];
  hseq[idx] = 0.2f * sh + 0.8f * shh;
}

// ---------------- weight prep: transposes + pos@W1a ----------------
__global__ void kprep_t(const float* __restrict__ w1W, const float* __restrict__ g1W,
                        const float* __restrict__ g2W, float* __restrict__ w1t2,
                        float* __restrict__ g1t, float* __restrict__ g2t) {
  int idx = blockIdx.x * 256 + threadIdx.x;
  if (idx >= 10000) return;
  int c = idx / 100, o = idx % 100;
  w1t2[c * 100 + o] = w1W[o * 200 + 100 + c];
  g1t[c * 100 + o] = g1W[o * 100 + c];
  g2t[c * 100 + o] = g2W[o * 100 + c];
}

__global__ void kprep_pos(const float* __restrict__ posE, const float* __restrict__ w1W,
                          const float* __restrict__ w1b, float* __restrict__ posW) {
  int idx = blockIdx.x * 256 + threadIdx.x;
  if (idx >= 5000) return;
  int l = idx / 100, o = idx % 100;
  float acc = w1b[o];
  for (int c = 0; c < 100; ++c) acc += posE[l * 100 + c] * w1W[o * 200 + c];
  posW[idx] = acc;
}

// ---------------- soft attention (block per batch) ----------------
__global__ __launch_bounds__(256) void ksoft(
    const float* __restrict__ hseqG, const float* __restrict__ slenp,
    const int* __restrict__ maskp,
    const float* __restrict__ posW, const float* __restrict__ w1t2,
    const float* __restrict__ glu1t, const float* __restrict__ glu1b,
    const float* __restrict__ glu2t, const float* __restrict__ w2,
    float* __restrict__ sel) {
  __shared__ float hq[LL * 101];
  __shared__ float nh[LL * 100];
  __shared__ float hs_s[100];
  __shared__ float g_s[100];
  __shared__ float beta_s[LL];
  int b = blockIdx.x, tid = threadIdx.x;
  for (int idx = tid; idx < LL * 100; idx += 256) {
    int l = idx / 100, d = idx % 100;
    hq[l * 101 + d] = hseqG[((size_t)b * LL + l) * 100 + d];
  }
  __syncthreads();
  if (tid < 100) {
    float s = 0.f;
    for (int l = 0; l < LL; ++l) s += hq[l * 101 + tid];
    hs_s[tid] = s / slenp[b];
  }
  __syncthreads();
  if (tid < 100) {
    float acc = 0.f;
    for (int c = 0; c < 100; ++c) acc += hs_s[c] * glu2t[c * 100 + tid];
    g_s[tid] = acc;
  }
  for (int idx = tid; idx < LL * 100; idx += 256) {
    int l = idx / 100, o = idx % 100;
    float acc = posW[idx];
    for (int c = 0; c < 100; ++c) acc += hq[l * 101 + c] * w1t2[c * 100 + o];
    nh[idx] = tanhf(acc);
  }
  __syncthreads();
  float vals[20];
  int cnt = 0;
  for (int idx = tid; idx < LL * 100; idx += 256) {
    int l = idx / 100, o = idx % 100;
    float acc = g_s[o] + glu1b[o];
    for (int c = 0; c < 100; ++c) acc += nh[l * 100 + c] * glu1t[c * 100 + o];
    float sg = 1.f / (1.f + expf(-acc));
    vals[cnt++] = sg * w2[o];
  }
  __syncthreads();
  cnt = 0;
  for (int idx = tid; idx < LL * 100; idx += 256) nh[idx] = vals[cnt++];
  __syncthreads();
  int w = tid >> 6, lane = tid & 63;
  for (int l = w; l < LL; l += 4) {
    float s = nh[l * 100 + lane];
    if (lane + 64 < 100) s += nh[l * 100 + lane + 64];
    #pragma unroll
    for (int off = 32; off; off >>= 1) s += __shfl_xor(s, off);
    if (lane == 0) beta_s[l] = s * (float)maskp[b * LL + l];
  }
  __syncthreads();
  if (tid < 100) {
    float acc = 0.f;
    for (int l = 0; l < LL; ++l) acc += beta_s[l] * hq[l * 101 + tid];
    sel[(size_t)b * 100 + tid] = acc;
  }
}

// ---------------- session conv: dense [512,512] @ [512,100] ----------------
__global__ void ksess(const float* __restrict__ adjS, const float* __restrict__ x,
                      float* __restrict__ out) {
  int b = blockIdx.x, d = threadIdx.x;
  if (d >= 100) return;
  const float* ar = adjS + (size_t)b * BB;
  float a0 = 0.f, a1 = 0.f, a2 = 0.f, a3 = 0.f;
  for (int j = 0; j < BB; j += 4) {
    a0 += ar[j]     * x[(j)     * 100 + d];
    a1 += ar[j + 1] * x[(j + 1) * 100 + d];
    a2 += ar[j + 2] * x[(j + 2) * 100 + d];
    a3 += ar[j + 3] * x[(j + 3) * 100 + d];
  }
  out[(size_t)b * 100 + d] = (a0 + a1) + (a2 + a3);
}

__global__ void ksesscomb(const float* __restrict__ x0, const float* __restrict__ x1,
                          const float* __restrict__ x2, const float* __restrict__ aS,
                          float* __restrict__ out) {
  int b = blockIdx.x * 4 + (threadIdx.x >> 6);
  int lane = threadIdx.x & 63;
  int d0 = lane, d1 = lane + 64;
  bool h1 = d1 < EMB;
  size_t base = (size_t)b * EMB;
  float v00 = x0[base + d0], v01 = h1 ? x0[base + d1] : 0.f;
  float v10 = x1[base + d0], v11 = h1 ? x1[base + d1] : 0.f;
  float v20 = x2[base + d0], v21 = h1 ? x2[base + d1] : 0.f;
  float q0 = v00 * v00 + v01 * v01;
  float q1 = v10 * v10 + v11 * v11;
  float q2 = v20 * v20 + v21 * v21;
  #pragma unroll
  for (int off = 32; off; off >>= 1) {
    q0 += __shfl_xor(q0, off);
    q1 += __shfl_xor(q1, off);
    q2 += __shfl_xor(q2, off);
  }
  float r0 = 1.f / fmaxf(sqrtf(q0), 1e-12f);
  float r1 = 1.f / fmaxf(sqrtf(q1), 1e-12f);
  float r2 = 1.f / fmaxf(sqrtf(q2), 1e-12f);
  float b0 = aS[0], b1 = aS[1], b2 = aS[2];
  // seq_h = sel1+sel2 = 2 * session_conv output
  out[base + d0] = 2.f * (b0 * v00 * r0 + b1 * v10 * r1 + b2 * v20 * r2);
  if (h1) out[base + d1] = 2.f * (b0 * v01 * r0 + b1 * v11 * r1 + b2 * v21 * r2);
}

// ---------------- scores GEMM: [512,100] x [40000,100]^T -> f32 out ----------------
__global__ __launch_bounds__(256) void kscores(const float* __restrict__ seqh,
                                               const float* __restrict__ emb,
                                               float* __restrict__ outS) {
  __shared__ float Sl[100 * 68];
  __shared__ float Gl[100 * 68];
  int n0 = blockIdx.x * 64, b0 = blockIdx.y * 64;
  int tid = threadIdx.x;
  for (int idx = tid; idx < 6400; idx += 256) {
    int r = idx / 100, c = idx % 100;
    Sl[c * 68 + r] = seqh[(size_t)(b0 + r) * 100 + c];
    Gl[c * 68 + r] = 2.f * emb[(size_t)(n0 + r) * 100 + c];  // embeddings = 2*emb_gnn
  }
  __syncthreads();
  int tx = tid & 15, ty = tid >> 4;
  float acc[4][4];
  #pragma unroll
  for (int i = 0; i < 4; i++)
    #pragma unroll
    for (int j = 0; j < 4; j++) acc[i][j] = 0.f;
  for (int c = 0; c < 100; ++c) {
    float4 sv = *(const float4*)&Sl[c * 68 + ty * 4];
    float4 gv = *(const float4*)&Gl[c * 68 + tx * 4];
    float ss[4] = {sv.x, sv.y, sv.z, sv.w};
    float gg[4] = {gv.x, gv.y, gv.z, gv.w};
    #pragma unroll
    for (int i = 0; i < 4; i++)
      #pragma unroll
      for (int j = 0; j < 4; j++) acc[i][j] += ss[i] * gg[j];
  }
  #pragma unroll
  for (int i = 0; i < 4; i++) {
    int b = b0 + ty * 4 + i;
    size_t base = (size_t)b * N_NODE + n0 + tx * 4;
    float2 p0 = make_float2(acc[i][0], acc[i][1]);
    float2 p1 = make_float2(acc[i][2], acc[i][3]);
    *(float2*)&outS[base] = p0;
    *(float2*)&outS[base + 2] = p1;
  }
}

// ---------------- per-row logsumexp + target score ----------------
__global__ __launch_bounds__(256) void klse(const float* __restrict__ outS,
                                            const int* __restrict__ tar,
                                            float* __restrict__ part) {
  __shared__ float ms[256], ss[256];
  int b = blockIdx.x, tid = threadIdx.x;
  const float2* sp = (const float2*)(outS + (size_t)b * N_NODE);
  float m = -INFINITY, s = 0.f;
  for (int i = tid; i < N_NODE / 2; i += 256) {
    float2 v = sp[i];
    float mx = fmaxf(v.x, v.y);
    float add = expf(v.x - mx) + expf(v.y - mx);
    if (mx > m) { s = s * expf(m - mx) + add; m = mx; }
    else s += add * expf(mx - m);
  }
  ms[tid] = m; ss[tid] = s;
  __syncthreads();
  for (int st = 128; st; st >>= 1) {
    if (tid < st) {
      float m2 = ms[tid + st], s2 = ss[tid + st];
      float M = fmaxf(ms[tid], m2);
      ss[tid] = ss[tid] * expf(ms[tid] - M) + s2 * expf(m2 - M);
      ms[tid] = M;
    }
    __syncthreads();
  }
  if (tid == 0) {
    float tsc = outS[(size_t)b * N_NODE + tar[b]];
    part[b] = tsc - (ms[0] + logf(ss[0]));
  }
}

__global__ void kfinal(const float* __restrict__ part, float* __restrict__ out) {
  __shared__ float red[256];
  int tid = threadIdx.x;
  red[tid] = part[tid] + part[tid + 256];
  __syncthreads();
  for (int st = 128; st; st >>= 1) {
    if (tid < st) red[tid] += red[tid + st];
    __syncthreads();
  }
  if (tid == 0) {
    out[0] = 0.f;                        // con_loss
    out[1] = -red[0] / (float)BB;        // loss
  }
}

extern "C" void kernel_launch(void* const* d_in, const int* in_sizes, int n_in,
                              void* d_out, int out_size, void* d_ws, size_t ws_size,
                              hipStream_t stream) {
  const int* tar    = (const int*)d_in[0];
  const int* rev    = (const int*)d_in[1];
  const int* maskp  = (const int*)d_in[2];
  const float* slen = (const float*)d_in[3];
  const float* sadj = (const float*)d_in[4];
  const int* items  = (const int*)d_in[6];
  const int* adjp   = (const int*)d_in[7];
  const int* alias  = (const int*)d_in[8];
  const int* grows  = (const int*)d_in[9];
  const int* gcols  = (const int*)d_in[10];
  const float* gvals = (const float*)d_in[11];
  const float* nemb = (const float*)d_in[12];
  const float* bI   = (const float*)d_in[13];
  const float* aS   = (const float*)d_in[14];
  const float* a0p  = (const float*)d_in[15];
  const float* a1p  = (const float*)d_in[16];
  const float* a2p  = (const float*)d_in[17];
  const float* a3p  = (const float*)d_in[18];
  const float* w1W  = (const float*)d_in[19];
  const float* w1b  = (const float*)d_in[20];
  const float* w2p  = (const float*)d_in[21];
  const float* g1W  = (const float*)d_in[22];
  const float* g1b  = (const float*)d_in[23];
  const float* g2W  = (const float*)d_in[24];
  const float* posE = (const float*)d_in[25];

  float* W = (float*)d_ws;
  size_t o = 0;
  float* emb_gnn = W + o; o += (size_t)N_NODE * EMB;   // 4,000,000
  float* x1      = W + o; o += (size_t)N_NODE * EMB;   // reused: hgat
  float* x2      = W + o; o += (size_t)N_NODE * EMB;   // reused: hseq
  float* sel     = W + o; o += (size_t)BB * EMB;
  float* y1      = W + o; o += (size_t)BB * EMB;
  float* y2      = W + o; o += (size_t)BB * EMB;
  float* seqh    = W + o; o += (size_t)BB * EMB;
  float* posW    = W + o; o += 5120;
  float* w1t2    = W + o; o += 10000;
  float* glu1t   = W + o; o += 10000;
  float* glu2t   = W + o; o += 10000;
  float* valS    = W + o; o += EDG;
  float* part    = W + o; o += 512;
  int* colS   = (int*)(W + o); o += EDG;
  int* counts = (int*)(W + o); o += N_NODE;
  int* starts = (int*)(W + o); o += N_NODE;
  int* cursor = (int*)(W + o); o += N_NODE;
  int* scantmp = (int*)(W + o); o += N_NODE;
  int* blocksums = (int*)(W + o); o += 256;
  // hgat/hseq alias x1/x2 (dead after kcomb); 2.56e6 <= 4e6 each
  float* hgat = x1;
  float* hseq = x2;

  float* outF = (float*)d_out;
  float* outScores = outF + 2;

  hipMemsetAsync(counts, 0, N_NODE * sizeof(int), stream);
  khist<<<EDG / 256, 256, 0, stream>>>(grows, counts);
  kscan1<<<SCAN_BLOCKS, 256, 0, stream>>>(counts, scantmp, blocksums, N_NODE);
  kscan2<<<1, 256, 0, stream>>>(blocksums, SCAN_BLOCKS);
  kscan3<<<SCAN_BLOCKS, 256, 0, stream>>>(scantmp, blocksums, starts, cursor, N_NODE);
  kfill<<<EDG / 256, 256, 0, stream>>>(grows, gcols, gvals, cursor, colS, valS);
  kspmm<<<N_NODE / 4, 256, 0, stream>>>(starts, counts, colS, valS, nemb, x1);
  kspmm<<<N_NODE / 4, 256, 0, stream>>>(starts, counts, colS, valS, x1, x2);
  kcomb<<<N_NODE / 4, 256, 0, stream>>>(nemb, x1, x2, bI, emb_gnn);
  kgat<<<BB, 256, 0, stream>>>(emb_gnn, items, adjp, a0p, a1p, a2p, a3p, hgat);
  kseq<<<(BB * LL * EMB) / 256, 256, 0, stream>>>(emb_gnn, rev, alias, hgat, hseq);
  kprep_t<<<40, 256, 0, stream>>>(w1W, g1W, g2W, w1t2, glu1t, glu2t);
  kprep_pos<<<20, 256, 0, stream>>>(posE, w1W, w1b, posW);
  ksoft<<<BB, 256, 0, stream>>>(hseq, slen, maskp, posW, w1t2, glu1t, g1b, glu2t, w2p, sel);
  ksess<<<BB, 128, 0, stream>>>(sadj, sel, y1);
  ksess<<<BB, 128, 0, stream>>>(sadj, y1, y2);
  ksesscomb<<<BB / 4, 256, 0, stream>>>(sel, y1, y2, aS, seqh);
  kscores<<<dim3(N_NODE / 64, BB / 64), 256, 0, stream>>>(seqh, emb_gnn, outScores);
  klse<<<BB, 256, 0, stream>>>(outScores, tar, part);
  kfinal<<<1, 256, 0, stream>>>(part, outF);
}

// Round 4
// 723.404 us; speedup vs baseline: 1.5255x; 1.1189x over previous
//
#include <hip/hip_runtime.h>
#include <math.h>

#define N_NODE 40000
#define EMB 100
#define BB 512
#define LL 50
#define NI 50
#define EDG 800000
#define SCAN_BLOCKS 157  // ceil(40000/256)

// ---------------- CSR build ----------------
__global__ void khist(const int* __restrict__ rows, int* __restrict__ counts) {
  int e = blockIdx.x * 256 + threadIdx.x;
  atomicAdd(&counts[rows[e]], 1);
}

// block-local exclusive scan (256 elems/block) + block sums
__global__ __launch_bounds__(256) void kscan1(const int* __restrict__ counts,
                                              int* __restrict__ scanout,
                                              int* __restrict__ blocksums, int n) {
  __shared__ int wsum[4];
  int tid = threadIdx.x;
  int i = blockIdx.x * 256 + tid;
  int v = (i < n) ? counts[i] : 0;
  int x = v;
  #pragma unroll
  for (int off = 1; off < 64; off <<= 1) {
    int t = __shfl_up(x, off, 64);
    if ((tid & 63) >= off) x += t;
  }
  int w = tid >> 6, lane = tid & 63;
  if (lane == 63) wsum[w] = x;
  __syncthreads();
  int woff = 0;
  #pragma unroll
  for (int k = 0; k < 4; ++k) woff += (k < w) ? wsum[k] : 0;
  int incl = x + woff;
  if (i < n) scanout[i] = incl - v;  // block-local exclusive
  if (tid == 255) blocksums[blockIdx.x] = incl;
}

// scan the block sums (one block, 256 threads >= 157)
__global__ __launch_bounds__(256) void kscan2(int* __restrict__ blocksums, int nb) {
  __shared__ int wsum[4];
  int tid = threadIdx.x;
  int v = (tid < nb) ? blocksums[tid] : 0;
  int x = v;
  #pragma unroll
  for (int off = 1; off < 64; off <<= 1) {
    int t = __shfl_up(x, off, 64);
    if ((tid & 63) >= off) x += t;
  }
  int w = tid >> 6, lane = tid & 63;
  if (lane == 63) wsum[w] = x;
  __syncthreads();
  int woff = 0;
  #pragma unroll
  for (int k = 0; k < 4; ++k) woff += (k < w) ? wsum[k] : 0;
  if (tid < nb) blocksums[tid] = x + woff - v;  // exclusive
}

// add block offsets, produce starts + cursor
__global__ __launch_bounds__(256) void kscan3(const int* __restrict__ scanout,
                                              const int* __restrict__ blocksums,
                                              int* __restrict__ starts,
                                              int* __restrict__ cursor, int n) {
  int i = blockIdx.x * 256 + threadIdx.x;
  if (i < n) {
    int s = scanout[i] + blocksums[blockIdx.x];
    starts[i] = s;
    cursor[i] = s;
  }
}

__global__ void kfill(const int* __restrict__ rows, const int* __restrict__ cols,
                      const float* __restrict__ vals, int* __restrict__ cursor,
                      int* __restrict__ colS, float* __restrict__ valS) {
  int e = blockIdx.x * 256 + threadIdx.x;
  int r = rows[e];
  int p = atomicAdd(&cursor[r], 1);
  colS[p] = cols[e];
  valS[p] = vals[e];
}

// ---------------- gather SpMM (wave per row) ----------------
__global__ void kspmm(const int* __restrict__ starts, const int* __restrict__ counts,
                      const int* __restrict__ colS, const float* __restrict__ valS,
                      const float* __restrict__ x, float* __restrict__ out) {
  int row = blockIdx.x * 4 + (threadIdx.x >> 6);
  int lane = threadIdx.x & 63;
  int s = starts[row], cnt = counts[row];
  int d0 = lane, d1 = lane + 64;
  bool h1 = d1 < EMB;
  float a0 = 0.f, a1 = 0.f;
  for (int t = 0; t < cnt; ++t) {
    int c = colS[s + t];
    float v = valS[s + t];
    const float* xr = x + (size_t)c * EMB;
    a0 += v * xr[d0];
    if (h1) a1 += v * xr[d1];
  }
  out[(size_t)row * EMB + d0] = a0;
  if (h1) out[(size_t)row * EMB + d1] = a1;
}

// ---------------- l2norm-combine (item conv epilogue) ----------------
__global__ void kcomb(const float* __restrict__ x0, const float* __restrict__ x1,
                      const float* __restrict__ x2, const float* __restrict__ bI,
                      float* __restrict__ emb) {
  int n = blockIdx.x * 4 + (threadIdx.x >> 6);
  int lane = threadIdx.x & 63;
  int d0 = lane, d1 = lane + 64;
  bool h1 = d1 < EMB;
  size_t base = (size_t)n * EMB;
  float v00 = x0[base + d0], v01 = h1 ? x0[base + d1] : 0.f;
  float v10 = x1[base + d0], v11 = h1 ? x1[base + d1] : 0.f;
  float v20 = x2[base + d0], v21 = h1 ? x2[base + d1] : 0.f;
  float q0 = v00 * v00 + v01 * v01;
  float q1 = v10 * v10 + v11 * v11;
  float q2 = v20 * v20 + v21 * v21;
  #pragma unroll
  for (int off = 32; off; off >>= 1) {
    q0 += __shfl_xor(q0, off);
    q1 += __shfl_xor(q1, off);
    q2 += __shfl_xor(q2, off);
  }
  float r0 = 1.f / fmaxf(sqrtf(q0), 1e-12f);
  float r1 = 1.f / fmaxf(sqrtf(q1), 1e-12f);
  float r2 = 1.f / fmaxf(sqrtf(q2), 1e-12f);
  float b0 = bI[0], b1 = bI[1], b2 = bI[2];
  emb[base + d0] = b0 * v00 * r0 + b1 * v10 * r1 + b2 * v20 * r2;
  if (h1) emb[base + d1] = b0 * v01 * r0 + b1 * v11 * r1 + b2 * v21 * r2;
}

// ---------------- GAT (block per batch, wave per row) ----------------
__global__ __launch_bounds__(256) void kgat(
    const float* __restrict__ emb, const int* __restrict__ items,
    const int* __restrict__ adj,
    const float* __restrict__ a0p, const float* __restrict__ a1p,
    const float* __restrict__ a2p, const float* __restrict__ a3p,
    float* __restrict__ hgat) {
  __shared__ float hl[NI * 101 + 80];
  __shared__ float as[4 * 100];
  __shared__ float al[4 * 64];
  int b = blockIdx.x;
  int tid = threadIdx.x;
  for (int idx = tid; idx < 400; idx += 256) {
    int k = idx / 100, d = idx % 100;
    const float* ap = (k == 0) ? a0p : (k == 1) ? a1p : (k == 2) ? a2p : a3p;
    as[idx] = ap[d];
  }
  for (int idx = tid; idx < NI * 100; idx += 256) {
    int i = idx / 100, d = idx % 100;
    int node = items[b * NI + i];
    hl[i * 101 + d] = (node == 0) ? 0.f : emb[(size_t)(node - 1) * EMB + d];
  }
  __syncthreads();
  int w = tid >> 6, lane = tid & 63;
  for (int i = w; i < NI; i += 4) {
    float s0 = 0, s1 = 0, s2 = 0, s3 = 0;
    if (lane < NI) {
      const float* hi = &hl[i * 101];
      const float* hj = &hl[lane * 101];
      for (int d = 0; d < 100; ++d) {
        float p = hi[d] * hj[d];
        s0 += p * as[d];
        s1 += p * as[100 + d];
        s2 += p * as[200 + d];
        s3 += p * as[300 + d];
      }
    }
    float e = -INFINITY;
    if (lane < NI) {
      int av = adj[(size_t)b * (NI * NI) + i * NI + lane];
      float sv = (av == 1) ? s0 : (av == 2) ? s1 : (av == 3) ? s2 : s3;
      sv = (sv >= 0.f) ? sv : 0.2f * sv;
      e = (av == 0) ? -9e15f : sv;
    }
    float m = e;
    #pragma unroll
    for (int off = 32; off; off >>= 1) m = fmaxf(m, __shfl_xor(m, off));
    float p = (lane < NI) ? expf(e - m) : 0.f;
    float ssum = p;
    #pragma unroll
    for (int off = 32; off; off >>= 1) ssum += __shfl_xor(ssum, off);
    al[w * 64 + lane] = p / ssum;
    int d0 = lane, d1 = lane + 64;
    float acc0 = 0.f, acc1 = 0.f;
    for (int j = 0; j < NI; ++j) {
      float a = al[w * 64 + j];
      acc0 += a * hl[j * 101 + d0];
      acc1 += a * hl[j * 101 + d1];  // padded array: safe garbage for d1>=100
    }
    size_t ob = ((size_t)b * NI + i) * EMB;
    hgat[ob + d0] = acc0;
    if (d1 < EMB) hgat[ob + d1] = acc1;
  }
}

// ---------------- get_seq mix ----------------
__global__ void kseq(const float* __restrict__ emb, const int* __restrict__ rev,
                     const int* __restrict__ alias, const float* __restrict__ hgat,
                     float* __restrict__ hseq) {
  int idx = blockIdx.x * 256 + threadIdx.x;  // 2,560,000 exact
  int b = idx / 5000, r = idx % 5000, l = r / 100, d = r % 100;
  int node = rev[b * LL + l];
  float sh = (node == 0) ? 0.f : emb[(size_t)(node - 1) * EMB + d];
  int a = alias[b * LL + l];
  float shh = hgat[((size_t)b * NI + a) * EMB + d];
  hseq[idx] = 0.2f * sh + 0.8f * shh;
}

// ---------------- weight prep: transposes + pos@W1a ----------------
__global__ void kprep_t(const float* __restrict__ w1W, const float* __restrict__ g1W,
                        const float* __restrict__ g2W, float* __restrict__ w1t2,
                        float* __restrict__ g1t, float* __restrict__ g2t) {
  int idx = blockIdx.x * 256 + threadIdx.x;
  if (idx >= 10000) return;
  int c = idx / 100, o = idx % 100;
  w1t2[c * 100 + o] = w1W[o * 200 + 100 + c];
  g1t[c * 100 + o] = g1W[o * 100 + c];
  g2t[c * 100 + o] = g2W[o * 100 + c];
}

__global__ void kprep_pos(const float* __restrict__ posE, const float* __restrict__ w1W,
                          const float* __restrict__ w1b, float* __restrict__ posW) {
  int idx = blockIdx.x * 256 + threadIdx.x;
  if (idx >= 5000) return;
  int l = idx / 100, o = idx % 100;
  float acc = w1b[o];
  for (int c = 0; c < 100; ++c) acc += posE[l * 100 + c] * w1W[o * 200 + c];
  posW[idx] = acc;
}

// ---------------- soft attention (block per batch, register-tiled) ----------------
// Threads 0..249: thread t computes a 5(l) x 4(o) output tile: lg=t/25, og=t%25.
// Weights read as float4 from global (L1/L2-resident 40KB), hq from LDS (broadcast).
__global__ __launch_bounds__(256) void ksoft(
    const float* __restrict__ hseqG, const float* __restrict__ slenp,
    const int* __restrict__ maskp,
    const float* __restrict__ posW, const float* __restrict__ w1t2,
    const float* __restrict__ glu1t, const float* __restrict__ glu1b,
    const float* __restrict__ glu2t, const float* __restrict__ w2,
    float* __restrict__ sel) {
  __shared__ float hq[LL * 101];       // 20.2 KB
  __shared__ float nh[LL * 100];       // 20 KB
  __shared__ float red[25 * 52];       // 5.2 KB  (red[og][l])
  __shared__ float hs_s[100];
  __shared__ float g_s[100];
  __shared__ float beta_s[LL];
  int b = blockIdx.x, tid = threadIdx.x;
  for (int idx = tid; idx < LL * 100; idx += 256) {
    int l = idx / 100, d = idx % 100;
    hq[l * 101 + d] = hseqG[((size_t)b * LL + l) * 100 + d];
  }
  __syncthreads();
  if (tid < 100) {
    float s = 0.f;
    for (int l = 0; l < LL; ++l) s += hq[l * 101 + tid];
    hs_s[tid] = s / slenp[b];
  }
  __syncthreads();
  if (tid < 100) {
    float acc = 0.f;
    for (int c = 0; c < 100; ++c) acc += hs_s[c] * glu2t[c * 100 + tid];
    g_s[tid] = acc;
  }
  // ---- phase B: nh = tanh(hq @ w1t2 + posW) ----
  int lg = tid / 25, og = tid % 25;    // valid when tid < 250
  if (tid < 250) {
    float acc[5][4];
    #pragma unroll
    for (int j = 0; j < 5; ++j) {
      float4 p = *(const float4*)&posW[(lg * 5 + j) * 100 + og * 4];
      acc[j][0] = p.x; acc[j][1] = p.y; acc[j][2] = p.z; acc[j][3] = p.w;
    }
    for (int c = 0; c < 100; ++c) {
      float4 wv = *(const float4*)&w1t2[c * 100 + og * 4];
      float hv[5];
      #pragma unroll
      for (int j = 0; j < 5; ++j) hv[j] = hq[(lg * 5 + j) * 101 + c];
      #pragma unroll
      for (int j = 0; j < 5; ++j) {
        acc[j][0] += hv[j] * wv.x;
        acc[j][1] += hv[j] * wv.y;
        acc[j][2] += hv[j] * wv.z;
        acc[j][3] += hv[j] * wv.w;
      }
    }
    #pragma unroll
    for (int j = 0; j < 5; ++j) {
      float4 t;
      t.x = tanhf(acc[j][0]); t.y = tanhf(acc[j][1]);
      t.z = tanhf(acc[j][2]); t.w = tanhf(acc[j][3]);
      *(float4*)&nh[(lg * 5 + j) * 100 + og * 4] = t;
    }
  }
  __syncthreads();  // nh + g_s visible
  // ---- phase C: val = sigmoid(nh @ glu1t + g + b) * w2; row-sum -> red ----
  if (tid < 250) {
    float4 gb = *(const float4*)&glu1b[og * 4];
    float4 gg = *(const float4*)&g_s[og * 4];
    float base0 = gg.x + gb.x, base1 = gg.y + gb.y, base2 = gg.z + gb.z, base3 = gg.w + gb.w;
    float acc[5][4];
    #pragma unroll
    for (int j = 0; j < 5; ++j) {
      acc[j][0] = base0; acc[j][1] = base1; acc[j][2] = base2; acc[j][3] = base3;
    }
    for (int c = 0; c < 100; ++c) {
      float4 wv = *(const float4*)&glu1t[c * 100 + og * 4];
      float hv[5];
      #pragma unroll
      for (int j = 0; j < 5; ++j) hv[j] = nh[(lg * 5 + j) * 100 + c];
      #pragma unroll
      for (int j = 0; j < 5; ++j) {
        acc[j][0] += hv[j] * wv.x;
        acc[j][1] += hv[j] * wv.y;
        acc[j][2] += hv[j] * wv.z;
        acc[j][3] += hv[j] * wv.w;
      }
    }
    float4 w2v = *(const float4*)&w2[og * 4];
    #pragma unroll
    for (int j = 0; j < 5; ++j) {
      float s0 = w2v.x / (1.f + expf(-acc[j][0]));
      float s1 = w2v.y / (1.f + expf(-acc[j][1]));
      float s2 = w2v.z / (1.f + expf(-acc[j][2]));
      float s3 = w2v.w / (1.f + expf(-acc[j][3]));
      red[og * 52 + lg * 5 + j] = (s0 + s1) + (s2 + s3);
    }
  }
  __syncthreads();
  if (tid < LL) {
    float s = 0.f;
    for (int og2 = 0; og2 < 25; ++og2) s += red[og2 * 52 + tid];
    beta_s[tid] = s * (float)maskp[b * LL + tid];
  }
  __syncthreads();
  if (tid < 100) {
    float acc = 0.f;
    for (int l = 0; l < LL; ++l) acc += beta_s[l] * hq[l * 101 + tid];
    sel[(size_t)b * 100 + tid] = acc;
  }
}

// ---------------- session conv: dense [512,512] @ [512,100] ----------------
__global__ void ksess(const float* __restrict__ adjS, const float* __restrict__ x,
                      float* __restrict__ out) {
  int b = blockIdx.x, d = threadIdx.x;
  if (d >= 100) return;
  const float* ar = adjS + (size_t)b * BB;
  float a0 = 0.f, a1 = 0.f, a2 = 0.f, a3 = 0.f;
  for (int j = 0; j < BB; j += 4) {
    a0 += ar[j]     * x[(j)     * 100 + d];
    a1 += ar[j + 1] * x[(j + 1) * 100 + d];
    a2 += ar[j + 2] * x[(j + 2) * 100 + d];
    a3 += ar[j + 3] * x[(j + 3) * 100 + d];
  }
  out[(size_t)b * 100 + d] = (a0 + a1) + (a2 + a3);
}

__global__ void ksesscomb(const float* __restrict__ x0, const float* __restrict__ x1,
                          const float* __restrict__ x2, const float* __restrict__ aS,
                          float* __restrict__ out) {
  int b = blockIdx.x * 4 + (threadIdx.x >> 6);
  int lane = threadIdx.x & 63;
  int d0 = lane, d1 = lane + 64;
  bool h1 = d1 < EMB;
  size_t base = (size_t)b * EMB;
  float v00 = x0[base + d0], v01 = h1 ? x0[base + d1] : 0.f;
  float v10 = x1[base + d0], v11 = h1 ? x1[base + d1] : 0.f;
  float v20 = x2[base + d0], v21 = h1 ? x2[base + d1] : 0.f;
  float q0 = v00 * v00 + v01 * v01;
  float q1 = v10 * v10 + v11 * v11;
  float q2 = v20 * v20 + v21 * v21;
  #pragma unroll
  for (int off = 32; off; off >>= 1) {
    q0 += __shfl_xor(q0, off);
    q1 += __shfl_xor(q1, off);
    q2 += __shfl_xor(q2, off);
  }
  float r0 = 1.f / fmaxf(sqrtf(q0), 1e-12f);
  float r1 = 1.f / fmaxf(sqrtf(q1), 1e-12f);
  float r2 = 1.f / fmaxf(sqrtf(q2), 1e-12f);
  float b0 = aS[0], b1 = aS[1], b2 = aS[2];
  // seq_h = sel1+sel2 = 2 * session_conv output
  out[base + d0] = 2.f * (b0 * v00 * r0 + b1 * v10 * r1 + b2 * v20 * r2);
  if (h1) out[base + d1] = 2.f * (b0 * v01 * r0 + b1 * v11 * r1 + b2 * v21 * r2);
}

// ---------------- scores GEMM: [512,100] x [40000,100]^T -> f32 out ----------------
__global__ __launch_bounds__(256) void kscores(const float* __restrict__ seqh,
                                               const float* __restrict__ emb,
                                               float* __restrict__ outS) {
  __shared__ float Sl[100 * 68];
  __shared__ float Gl[100 * 68];
  int n0 = blockIdx.x * 64, b0 = blockIdx.y * 64;
  int tid = threadIdx.x;
  for (int idx = tid; idx < 6400; idx += 256) {
    int r = idx / 100, c = idx % 100;
    Sl[c * 68 + r] = seqh[(size_t)(b0 + r) * 100 + c];
    Gl[c * 68 + r] = 2.f * emb[(size_t)(n0 + r) * 100 + c];  // embeddings = 2*emb_gnn
  }
  __syncthreads();
  int tx = tid & 15, ty = tid >> 4;
  float acc[4][4];
  #pragma unroll
  for (int i = 0; i < 4; i++)
    #pragma unroll
    for (int j = 0; j < 4; j++) acc[i][j] = 0.f;
  for (int c = 0; c < 100; ++c) {
    float4 sv = *(const float4*)&Sl[c * 68 + ty * 4];
    float4 gv = *(const float4*)&Gl[c * 68 + tx * 4];
    float ss[4] = {sv.x, sv.y, sv.z, sv.w};
    float gg[4] = {gv.x, gv.y, gv.z, gv.w};
    #pragma unroll
    for (int i = 0; i < 4; i++)
      #pragma unroll
      for (int j = 0; j < 4; j++) acc[i][j] += ss[i] * gg[j];
  }
  #pragma unroll
  for (int i = 0; i < 4; i++) {
    int b = b0 + ty * 4 + i;
    size_t base = (size_t)b * N_NODE + n0 + tx * 4;
    float2 p0 = make_float2(acc[i][0], acc[i][1]);
    float2 p1 = make_float2(acc[i][2], acc[i][3]);
    *(float2*)&outS[base] = p0;
    *(float2*)&outS[base + 2] = p1;
  }
}

// ---------------- per-row logsumexp + target score ----------------
__global__ __launch_bounds__(256) void klse(const float* __restrict__ outS,
                                            const int* __restrict__ tar,
                                            float* __restrict__ part) {
  __shared__ float ms[256], ss[256];
  int b = blockIdx.x, tid = threadIdx.x;
  const float2* sp = (const float2*)(outS + (size_t)b * N_NODE);
  float m = -INFINITY, s = 0.f;
  for (int i = tid; i < N_NODE / 2; i += 256) {
    float2 v = sp[i];
    float mx = fmaxf(v.x, v.y);
    float add = expf(v.x - mx) + expf(v.y - mx);
    if (mx > m) { s = s * expf(m - mx) + add; m = mx; }
    else s += add * expf(mx - m);
  }
  ms[tid] = m; ss[tid] = s;
  __syncthreads();
  for (int st = 128; st; st >>= 1) {
    if (tid < st) {
      float m2 = ms[tid + st], s2 = ss[tid + st];
      float M = fmaxf(ms[tid], m2);
      ss[tid] = ss[tid] * expf(ms[tid] - M) + s2 * expf(m2 - M);
      ms[tid] = M;
    }
    __syncthreads();
  }
  if (tid == 0) {
    float tsc = outS[(size_t)b * N_NODE + tar[b]];
    part[b] = tsc - (ms[0] + logf(ss[0]));
  }
}

__global__ void kfinal(const float* __restrict__ part, float* __restrict__ out) {
  __shared__ float red[256];
  int tid = threadIdx.x;
  red[tid] = part[tid] + part[tid + 256];
  __syncthreads();
  for (int st = 128; st; st >>= 1) {
    if (tid < st) red[tid] += red[tid + st];
    __syncthreads();
  }
  if (tid == 0) {
    out[0] = 0.f;                        // con_loss
    out[1] = -red[0] / (float)BB;        // loss
  }
}

extern "C" void kernel_launch(void* const* d_in, const int* in_sizes, int n_in,
                              void* d_out, int out_size, void* d_ws, size_t ws_size,
                              hipStream_t stream) {
  const int* tar    = (const int*)d_in[0];
  const int* rev    = (const int*)d_in[1];
  const int* maskp  = (const int*)d_in[2];
  const float* slen = (const float*)d_in[3];
  const float* sadj = (const float*)d_in[4];
  const int* items  = (const int*)d_in[6];
  const int* adjp   = (const int*)d_in[7];
  const int* alias  = (const int*)d_in[8];
  const int* grows  = (const int*)d_in[9];
  const int* gcols  = (const int*)d_in[10];
  const float* gvals = (const float*)d_in[11];
  const float* nemb = (const float*)d_in[12];
  const float* bI   = (const float*)d_in[13];
  const float* aS   = (const float*)d_in[14];
  const float* a0p  = (const float*)d_in[15];
  const float* a1p  = (const float*)d_in[16];
  const float* a2p  = (const float*)d_in[17];
  const float* a3p  = (const float*)d_in[18];
  const float* w1W  = (const float*)d_in[19];
  const float* w1b  = (const float*)d_in[20];
  const float* w2p  = (const float*)d_in[21];
  const float* g1W  = (const float*)d_in[22];
  const float* g1b  = (const float*)d_in[23];
  const float* g2W  = (const float*)d_in[24];
  const float* posE = (const float*)d_in[25];

  float* W = (float*)d_ws;
  size_t o = 0;
  float* emb_gnn = W + o; o += (size_t)N_NODE * EMB;   // 4,000,000
  float* x1      = W + o; o += (size_t)N_NODE * EMB;   // reused: hgat
  float* x2      = W + o; o += (size_t)N_NODE * EMB;   // reused: hseq
  float* sel     = W + o; o += (size_t)BB * EMB;
  float* y1      = W + o; o += (size_t)BB * EMB;
  float* y2      = W + o; o += (size_t)BB * EMB;
  float* seqh    = W + o; o += (size_t)BB * EMB;
  float* posW    = W + o; o += 5120;
  float* w1t2    = W + o; o += 10000;
  float* glu1t   = W + o; o += 10000;
  float* glu2t   = W + o; o += 10000;
  float* valS    = W + o; o += EDG;
  float* part    = W + o; o += 512;
  int* colS   = (int*)(W + o); o += EDG;
  int* counts = (int*)(W + o); o += N_NODE;
  int* starts = (int*)(W + o); o += N_NODE;
  int* cursor = (int*)(W + o); o += N_NODE;
  int* scantmp = (int*)(W + o); o += N_NODE;
  int* blocksums = (int*)(W + o); o += 256;
  // hgat/hseq alias x1/x2 (dead after kcomb); 2.56e6 <= 4e6 each
  float* hgat = x1;
  float* hseq = x2;

  float* outF = (float*)d_out;
  float* outScores = outF + 2;

  hipMemsetAsync(counts, 0, N_NODE * sizeof(int), stream);
  khist<<<EDG / 256, 256, 0, stream>>>(grows, counts);
  kscan1<<<SCAN_BLOCKS, 256, 0, stream>>>(counts, scantmp, blocksums, N_NODE);
  kscan2<<<1, 256, 0, stream>>>(blocksums, SCAN_BLOCKS);
  kscan3<<<SCAN_BLOCKS, 256, 0, stream>>>(scantmp, blocksums, starts, cursor, N_NODE);
  kfill<<<EDG / 256, 256, 0, stream>>>(grows, gcols, gvals, cursor, colS, valS);
  kspmm<<<N_NODE / 4, 256, 0, stream>>>(starts, counts, colS, valS, nemb, x1);
  kspmm<<<N_NODE / 4, 256, 0, stream>>>(starts, counts, colS, valS, x1, x2);
  kcomb<<<N_NODE / 4, 256, 0, stream>>>(nemb, x1, x2, bI, emb_gnn);
  kgat<<<BB, 256, 0, stream>>>(emb_gnn, items, adjp, a0p, a1p, a2p, a3p, hgat);
  kseq<<<(BB * LL * EMB) / 256, 256, 0, stream>>>(emb_gnn, rev, alias, hgat, hseq);
  kprep_t<<<40, 256, 0, stream>>>(w1W, g1W, g2W, w1t2, glu1t, glu2t);
  kprep_pos<<<20, 256, 0, stream>>>(posE, w1W, w1b, posW);
  ksoft<<<BB, 256, 0, stream>>>(hseq, slen, maskp, posW, w1t2, glu1t, g1b, glu2t, w2p, sel);
  ksess<<<BB, 128, 0, stream>>>(sadj, sel, y1);
  ksess<<<BB, 128, 0, stream>>>(sadj, y1, y2);
  ksesscomb<<<BB / 4, 256, 0, stream>>>(sel, y1, y2, aS, seqh);
  kscores<<<dim3(N_NODE / 64, BB / 64), 256, 0, stream>>>(seqh, emb_gnn, outScores);
  klse<<<BB, 256, 0, stream>>>(outScores, tar, part);
  kfinal<<<1, 256, 0, stream>>>(part, outF);
}

// Round 5
// 692.981 us; speedup vs baseline: 1.5924x; 1.0439x over previous
//
#include <hip/hip_runtime.h>
#include <hip/hip_bf16.h>
#include <math.h>

#define N_NODE 40000
#define EMB 100
#define BB 512
#define LL 50
#define NI 50
#define EDG 800000
#define SCAN_BLOCKS 157  // ceil(40000/256)

typedef short s16x8 __attribute__((ext_vector_type(8)));   // 8 bf16 = 4 VGPRs
typedef float f32x4 __attribute__((ext_vector_type(4)));   // MFMA 16x16 accumulator

// ---------------- CSR build ----------------
__global__ void khist(const int* __restrict__ rows, int* __restrict__ counts) {
  int e = blockIdx.x * 256 + threadIdx.x;
  atomicAdd(&counts[rows[e]], 1);
}

// block-local exclusive scan (256 elems/block) + block sums
__global__ __launch_bounds__(256) void kscan1(const int* __restrict__ counts,
                                              int* __restrict__ scanout,
                                              int* __restrict__ blocksums, int n) {
  __shared__ int wsum[4];
  int tid = threadIdx.x;
  int i = blockIdx.x * 256 + tid;
  int v = (i < n) ? counts[i] : 0;
  int x = v;
  #pragma unroll
  for (int off = 1; off < 64; off <<= 1) {
    int t = __shfl_up(x, off, 64);
    if ((tid & 63) >= off) x += t;
  }
  int w = tid >> 6, lane = tid & 63;
  if (lane == 63) wsum[w] = x;
  __syncthreads();
  int woff = 0;
  #pragma unroll
  for (int k = 0; k < 4; ++k) woff += (k < w) ? wsum[k] : 0;
  int incl = x + woff;
  if (i < n) scanout[i] = incl - v;  // block-local exclusive
  if (tid == 255) blocksums[blockIdx.x] = incl;
}

// scan the block sums (one block, 256 threads >= 157)
__global__ __launch_bounds__(256) void kscan2(int* __restrict__ blocksums, int nb) {
  __shared__ int wsum[4];
  int tid = threadIdx.x;
  int v = (tid < nb) ? blocksums[tid] : 0;
  int x = v;
  #pragma unroll
  for (int off = 1; off < 64; off <<= 1) {
    int t = __shfl_up(x, off, 64);
    if ((tid & 63) >= off) x += t;
  }
  int w = tid >> 6, lane = tid & 63;
  if (lane == 63) wsum[w] = x;
  __syncthreads();
  int woff = 0;
  #pragma unroll
  for (int k = 0; k < 4; ++k) woff += (k < w) ? wsum[k] : 0;
  if (tid < nb) blocksums[tid] = x + woff - v;  // exclusive
}

// add block offsets, produce starts + cursor
__global__ __launch_bounds__(256) void kscan3(const int* __restrict__ scanout,
                                              const int* __restrict__ blocksums,
                                              int* __restrict__ starts,
                                              int* __restrict__ cursor, int n) {
  int i = blockIdx.x * 256 + threadIdx.x;
  if (i < n) {
    int s = scanout[i] + blocksums[blockIdx.x];
    starts[i] = s;
    cursor[i] = s;
  }
}

__global__ void kfill(const int* __restrict__ rows, const int* __restrict__ cols,
                      const float* __restrict__ vals, int* __restrict__ cursor,
                      int* __restrict__ colS, float* __restrict__ valS) {
  int e = blockIdx.x * 256 + threadIdx.x;
  int r = rows[e];
  int p = atomicAdd(&cursor[r], 1);
  colS[p] = cols[e];
  valS[p] = vals[e];
}

// ---------------- gather SpMM (wave per row) ----------------
__global__ void kspmm(const int* __restrict__ starts, const int* __restrict__ counts,
                      const int* __restrict__ colS, const float* __restrict__ valS,
                      const float* __restrict__ x, float* __restrict__ out) {
  int row = blockIdx.x * 4 + (threadIdx.x >> 6);
  int lane = threadIdx.x & 63;
  int s = starts[row], cnt = counts[row];
  int d0 = lane, d1 = lane + 64;
  bool h1 = d1 < EMB;
  float a0 = 0.f, a1 = 0.f;
  for (int t = 0; t < cnt; ++t) {
    int c = colS[s + t];
    float v = valS[s + t];
    const float* xr = x + (size_t)c * EMB;
    a0 += v * xr[d0];
    if (h1) a1 += v * xr[d1];
  }
  out[(size_t)row * EMB + d0] = a0;
  if (h1) out[(size_t)row * EMB + d1] = a1;
}

// ---------------- l2norm-combine (item conv epilogue) ----------------
__global__ void kcomb(const float* __restrict__ x0, const float* __restrict__ x1,
                      const float* __restrict__ x2, const float* __restrict__ bI,
                      float* __restrict__ emb) {
  int n = blockIdx.x * 4 + (threadIdx.x >> 6);
  int lane = threadIdx.x & 63;
  int d0 = lane, d1 = lane + 64;
  bool h1 = d1 < EMB;
  size_t base = (size_t)n * EMB;
  float v00 = x0[base + d0], v01 = h1 ? x0[base + d1] : 0.f;
  float v10 = x1[base + d0], v11 = h1 ? x1[base + d1] : 0.f;
  float v20 = x2[base + d0], v21 = h1 ? x2[base + d1] : 0.f;
  float q0 = v00 * v00 + v01 * v01;
  float q1 = v10 * v10 + v11 * v11;
  float q2 = v20 * v20 + v21 * v21;
  #pragma unroll
  for (int off = 32; off; off >>= 1) {
    q0 += __shfl_xor(q0, off);
    q1 += __shfl_xor(q1, off);
    q2 += __shfl_xor(q2, off);
  }
  float r0 = 1.f / fmaxf(sqrtf(q0), 1e-12f);
  float r1 = 1.f / fmaxf(sqrtf(q1), 1e-12f);
  float r2 = 1.f / fmaxf(sqrtf(q2), 1e-12f);
  float b0 = bI[0], b1 = bI[1], b2 = bI[2];
  emb[base + d0] = b0 * v00 * r0 + b1 * v10 * r1 + b2 * v20 * r2;
  if (h1) emb[base + d1] = b0 * v01 * r0 + b1 * v11 * r1 + b2 * v21 * r2;
}

// ---------------- GAT (block per batch, wave per row) ----------------
__global__ __launch_bounds__(256) void kgat(
    const float* __restrict__ emb, const int* __restrict__ items,
    const int* __restrict__ adj,
    const float* __restrict__ a0p, const float* __restrict__ a1p,
    const float* __restrict__ a2p, const float* __restrict__ a3p,
    float* __restrict__ hgat) {
  __shared__ float hl[NI * 101 + 80];
  __shared__ float as[4 * 100];
  __shared__ float al[4 * 64];
  int b = blockIdx.x;
  int tid = threadIdx.x;
  for (int idx = tid; idx < 400; idx += 256) {
    int k = idx / 100, d = idx % 100;
    const float* ap = (k == 0) ? a0p : (k == 1) ? a1p : (k == 2) ? a2p : a3p;
    as[idx] = ap[d];
  }
  for (int idx = tid; idx < NI * 100; idx += 256) {
    int i = idx / 100, d = idx % 100;
    int node = items[b * NI + i];
    hl[i * 101 + d] = (node == 0) ? 0.f : emb[(size_t)(node - 1) * EMB + d];
  }
  __syncthreads();
  int w = tid >> 6, lane = tid & 63;
  for (int i = w; i < NI; i += 4) {
    float s0 = 0, s1 = 0, s2 = 0, s3 = 0;
    if (lane < NI) {
      const float* hi = &hl[i * 101];
      const float* hj = &hl[lane * 101];
      for (int d = 0; d < 100; ++d) {
        float p = hi[d] * hj[d];
        s0 += p * as[d];
        s1 += p * as[100 + d];
        s2 += p * as[200 + d];
        s3 += p * as[300 + d];
      }
    }
    float e = -INFINITY;
    if (lane < NI) {
      int av = adj[(size_t)b * (NI * NI) + i * NI + lane];
      float sv = (av == 1) ? s0 : (av == 2) ? s1 : (av == 3) ? s2 : s3;
      sv = (sv >= 0.f) ? sv : 0.2f * sv;
      e = (av == 0) ? -9e15f : sv;
    }
    float m = e;
    #pragma unroll
    for (int off = 32; off; off >>= 1) m = fmaxf(m, __shfl_xor(m, off));
    float p = (lane < NI) ? expf(e - m) : 0.f;
    float ssum = p;
    #pragma unroll
    for (int off = 32; off; off >>= 1) ssum += __shfl_xor(ssum, off);
    al[w * 64 + lane] = p / ssum;
    int d0 = lane, d1 = lane + 64;
    float acc0 = 0.f, acc1 = 0.f;
    for (int j = 0; j < NI; ++j) {
      float a = al[w * 64 + j];
      acc0 += a * hl[j * 101 + d0];
      acc1 += a * hl[j * 101 + d1];  // padded array: safe garbage for d1>=100
    }
    size_t ob = ((size_t)b * NI + i) * EMB;
    hgat[ob + d0] = acc0;
    if (d1 < EMB) hgat[ob + d1] = acc1;
  }
}

// ---------------- get_seq mix ----------------
__global__ void kseq(const float* __restrict__ emb, const int* __restrict__ rev,
                     const int* __restrict__ alias, const float* __restrict__ hgat,
                     float* __restrict__ hseq) {
  int idx = blockIdx.x * 256 + threadIdx.x;  // 2,560,000 exact
  int b = idx / 5000, r = idx % 5000, l = r / 100, d = r % 100;
  int node = rev[b * LL + l];
  float sh = (node == 0) ? 0.f : emb[(size_t)(node - 1) * EMB + d];
  int a = alias[b * LL + l];
  float shh = hgat[((size_t)b * NI + a) * EMB + d];
  hseq[idx] = 0.2f * sh + 0.8f * shh;
}

// ---------------- weight prep: transposes + pos@W1a ----------------
__global__ void kprep_t(const float* __restrict__ w1W, const float* __restrict__ g1W,
                        const float* __restrict__ g2W, float* __restrict__ w1t2,
                        float* __restrict__ g1t, float* __restrict__ g2t) {
  int idx = blockIdx.x * 256 + threadIdx.x;
  if (idx >= 10000) return;
  int c = idx / 100, o = idx % 100;
  w1t2[c * 100 + o] = w1W[o * 200 + 100 + c];
  g1t[c * 100 + o] = g1W[o * 100 + c];
  g2t[c * 100 + o] = g2W[o * 100 + c];
}

__global__ void kprep_pos(const float* __restrict__ posE, const float* __restrict__ w1W,
                          const float* __restrict__ w1b, float* __restrict__ posW) {
  int idx = blockIdx.x * 256 + threadIdx.x;
  if (idx >= 5000) return;
  int l = idx / 100, o = idx % 100;
  float acc = w1b[o];
  for (int c = 0; c < 100; ++c) acc += posE[l * 100 + c] * w1W[o * 200 + c];
  posW[idx] = acc;
}

// ---------------- soft attention (block per batch, register-tiled) ----------------
__global__ __launch_bounds__(256) void ksoft(
    const float* __restrict__ hseqG, const float* __restrict__ slenp,
    const int* __restrict__ maskp,
    const float* __restrict__ posW, const float* __restrict__ w1t2,
    const float* __restrict__ glu1t, const float* __restrict__ glu1b,
    const float* __restrict__ glu2t, const float* __restrict__ w2,
    float* __restrict__ sel) {
  __shared__ float hq[LL * 101];       // 20.2 KB
  __shared__ float nh[LL * 100];       // 20 KB
  __shared__ float red[25 * 52];       // 5.2 KB  (red[og][l])
  __shared__ float hs_s[100];
  __shared__ float g_s[100];
  __shared__ float beta_s[LL];
  int b = blockIdx.x, tid = threadIdx.x;
  for (int idx = tid; idx < LL * 100; idx += 256) {
    int l = idx / 100, d = idx % 100;
    hq[l * 101 + d] = hseqG[((size_t)b * LL + l) * 100 + d];
  }
  __syncthreads();
  if (tid < 100) {
    float s = 0.f;
    for (int l = 0; l < LL; ++l) s += hq[l * 101 + tid];
    hs_s[tid] = s / slenp[b];
  }
  __syncthreads();
  if (tid < 100) {
    float acc = 0.f;
    for (int c = 0; c < 100; ++c) acc += hs_s[c] * glu2t[c * 100 + tid];
    g_s[tid] = acc;
  }
  // ---- phase B: nh = tanh(hq @ w1t2 + posW) ----
  int lg = tid / 25, og = tid % 25;    // valid when tid < 250
  if (tid < 250) {
    float acc[5][4];
    #pragma unroll
    for (int j = 0; j < 5; ++j) {
      float4 p = *(const float4*)&posW[(lg * 5 + j) * 100 + og * 4];
      acc[j][0] = p.x; acc[j][1] = p.y; acc[j][2] = p.z; acc[j][3] = p.w;
    }
    for (int c = 0; c < 100; ++c) {
      float4 wv = *(const float4*)&w1t2[c * 100 + og * 4];
      float hv[5];
      #pragma unroll
      for (int j = 0; j < 5; ++j) hv[j] = hq[(lg * 5 + j) * 101 + c];
      #pragma unroll
      for (int j = 0; j < 5; ++j) {
        acc[j][0] += hv[j] * wv.x;
        acc[j][1] += hv[j] * wv.y;
        acc[j][2] += hv[j] * wv.z;
        acc[j][3] += hv[j] * wv.w;
      }
    }
    #pragma unroll
    for (int j = 0; j < 5; ++j) {
      float4 t;
      t.x = tanhf(acc[j][0]); t.y = tanhf(acc[j][1]);
      t.z = tanhf(acc[j][2]); t.w = tanhf(acc[j][3]);
      *(float4*)&nh[(lg * 5 + j) * 100 + og * 4] = t;
    }
  }
  __syncthreads();  // nh + g_s visible
  // ---- phase C: val = sigmoid(nh @ glu1t + g + b) * w2; row-sum -> red ----
  if (tid < 250) {
    float4 gb = *(const float4*)&glu1b[og * 4];
    float4 gg = *(const float4*)&g_s[og * 4];
    float base0 = gg.x + gb.x, base1 = gg.y + gb.y, base2 = gg.z + gb.z, base3 = gg.w + gb.w;
    float acc[5][4];
    #pragma unroll
    for (int j = 0; j < 5; ++j) {
      acc[j][0] = base0; acc[j][1] = base1; acc[j][2] = base2; acc[j][3] = base3;
    }
    for (int c = 0; c < 100; ++c) {
      float4 wv = *(const float4*)&glu1t[c * 100 + og * 4];
      float hv[5];
      #pragma unroll
      for (int j = 0; j < 5; ++j) hv[j] = nh[(lg * 5 + j) * 100 + c];
      #pragma unroll
      for (int j = 0; j < 5; ++j) {
        acc[j][0] += hv[j] * wv.x;
        acc[j][1] += hv[j] * wv.y;
        acc[j][2] += hv[j] * wv.z;
        acc[j][3] += hv[j] * wv.w;
      }
    }
    float4 w2v = *(const float4*)&w2[og * 4];
    #pragma unroll
    for (int j = 0; j < 5; ++j) {
      float s0 = w2v.x / (1.f + expf(-acc[j][0]));
      float s1 = w2v.y / (1.f + expf(-acc[j][1]));
      float s2 = w2v.z / (1.f + expf(-acc[j][2]));
      float s3 = w2v.w / (1.f + expf(-acc[j][3]));
      red[og * 52 + lg * 5 + j] = (s0 + s1) + (s2 + s3);
    }
  }
  __syncthreads();
  if (tid < LL) {
    float s = 0.f;
    for (int og2 = 0; og2 < 25; ++og2) s += red[og2 * 52 + tid];
    beta_s[tid] = s * (float)maskp[b * LL + tid];
  }
  __syncthreads();
  if (tid < 100) {
    float acc = 0.f;
    for (int l = 0; l < LL; ++l) acc += beta_s[l] * hq[l * 101 + tid];
    sel[(size_t)b * 100 + tid] = acc;
  }
}

// ---------------- session conv: dense [512,512] @ [512,100] ----------------
__global__ void ksess(const float* __restrict__ adjS, const float* __restrict__ x,
                      float* __restrict__ out) {
  int b = blockIdx.x, d = threadIdx.x;
  if (d >= 100) return;
  const float* ar = adjS + (size_t)b * BB;
  float a0 = 0.f, a1 = 0.f, a2 = 0.f, a3 = 0.f;
  for (int j = 0; j < BB; j += 4) {
    a0 += ar[j]     * x[(j)     * 100 + d];
    a1 += ar[j + 1] * x[(j + 1) * 100 + d];
    a2 += ar[j + 2] * x[(j + 2) * 100 + d];
    a3 += ar[j + 3] * x[(j + 3) * 100 + d];
  }
  out[(size_t)b * 100 + d] = (a0 + a1) + (a2 + a3);
}

__global__ void ksesscomb(const float* __restrict__ x0, const float* __restrict__ x1,
                          const float* __restrict__ x2, const float* __restrict__ aS,
                          float* __restrict__ out) {
  int b = blockIdx.x * 4 + (threadIdx.x >> 6);
  int lane = threadIdx.x & 63;
  int d0 = lane, d1 = lane + 64;
  bool h1 = d1 < EMB;
  size_t base = (size_t)b * EMB;
  float v00 = x0[base + d0], v01 = h1 ? x0[base + d1] : 0.f;
  float v10 = x1[base + d0], v11 = h1 ? x1[base + d1] : 0.f;
  float v20 = x2[base + d0], v21 = h1 ? x2[base + d1] : 0.f;
  float q0 = v00 * v00 + v01 * v01;
  float q1 = v10 * v10 + v11 * v11;
  float q2 = v20 * v20 + v21 * v21;
  #pragma unroll
  for (int off = 32; off; off >>= 1) {
    q0 += __shfl_xor(q0, off);
    q1 += __shfl_xor(q1, off);
    q2 += __shfl_xor(q2, off);
  }
  float r0 = 1.f / fmaxf(sqrtf(q0), 1e-12f);
  float r1 = 1.f / fmaxf(sqrtf(q1), 1e-12f);
  float r2 = 1.f / fmaxf(sqrtf(q2), 1e-12f);
  float b0 = aS[0], b1 = aS[1], b2 = aS[2];
  // seq_h = sel1+sel2 = 2 * session_conv output
  out[base + d0] = 2.f * (b0 * v00 * r0 + b1 * v10 * r1 + b2 * v20 * r2);
  if (h1) out[base + d1] = 2.f * (b0 * v01 * r0 + b1 * v11 * r1 + b2 * v21 * r2);
}

// ---------------- bf16 hi/lo split prep ----------------
// B = 2*emb_gnn -> [40000][128] padded; A = seqh -> [512][128] padded
__global__ void kprepB(const float* __restrict__ emb, unsigned short* __restrict__ bHi,
                       unsigned short* __restrict__ bLo) {
  int idx = blockIdx.x * 256 + threadIdx.x;  // 5,120,000 exact
  int n = idx >> 7, k = idx & 127;
  float v = (k < EMB) ? 2.f * emb[(size_t)n * EMB + k] : 0.f;
  __hip_bfloat16 h = __float2bfloat16(v);
  float rem = v - __bfloat162float(h);
  __hip_bfloat16 l = __float2bfloat16(rem);
  bHi[idx] = *reinterpret_cast<unsigned short*>(&h);
  bLo[idx] = *reinterpret_cast<unsigned short*>(&l);
}

__global__ void kprepA(const float* __restrict__ seqh, unsigned short* __restrict__ aHi,
                       unsigned short* __restrict__ aLo) {
  int idx = blockIdx.x * 256 + threadIdx.x;  // 65,536 exact
  int n = idx >> 7, k = idx & 127;
  float v = (k < EMB) ? seqh[(size_t)n * EMB + k] : 0.f;
  __hip_bfloat16 h = __float2bfloat16(v);
  float rem = v - __bfloat162float(h);
  __hip_bfloat16 l = __float2bfloat16(rem);
  aHi[idx] = *reinterpret_cast<unsigned short*>(&h);
  aLo[idx] = *reinterpret_cast<unsigned short*>(&l);
}

// ---------------- scores GEMM via split-bf16 MFMA ----------------
// C[b][n] = sum_k A[b][k] * B[n][k], K=128 (zero-padded from 100).
// Block: 64b x 64n, 4 waves; wave w: rows [b0+16w, +16), all 64 n.
// MFMA 16x16x32 bf16: A-frag A[m=lane&15][k=quad*8+j]; B-frag B[n=lane&15][k=quad*8+j];
// C/D: col(n)=lane&15, row(m)=quad*4+reg.  (learn_hip m89-verified mappings)
__global__ __launch_bounds__(256) void kscoresM(
    const unsigned short* __restrict__ aHi, const unsigned short* __restrict__ aLo,
    const unsigned short* __restrict__ bHi, const unsigned short* __restrict__ bLo,
    float* __restrict__ outS) {
  __shared__ __align__(16) unsigned short Bh[64 * 136];  // 136 = 128 + 8 pad (16B-mult rows)
  __shared__ __align__(16) unsigned short Bl[64 * 136];
  int tid = threadIdx.x;
  int n0 = blockIdx.x * 64, b0 = blockIdx.y * 64;
  int w = tid >> 6, lane = tid & 63;
  int ln = lane & 15, quad = lane >> 4;

  // A fragments straight from global (L2-hot: 256 KB total, reused by 625 n-blocks)
  const unsigned short* aRowH = aHi + (size_t)(b0 + w * 16 + ln) * 128 + quad * 8;
  const unsigned short* aRowL = aLo + (size_t)(b0 + w * 16 + ln) * 128 + quad * 8;
  s16x8 ah[4], al[4];
  #pragma unroll
  for (int s = 0; s < 4; ++s) {
    ah[s] = *(const s16x8*)(aRowH + s * 32);
    al[s] = *(const s16x8*)(aRowL + s * 32);
  }

  // stage B tile (64 rows x 128 k, hi+lo) into LDS
  #pragma unroll
  for (int it = 0; it < 4; ++it) {
    int seg = tid + it * 256;      // 0..1023
    int r = seg >> 4, q = seg & 15;
    *(s16x8*)&Bh[r * 136 + q * 8] = *(const s16x8*)&bHi[(size_t)(n0 + r) * 128 + q * 8];
    *(s16x8*)&Bl[r * 136 + q * 8] = *(const s16x8*)&bLo[(size_t)(n0 + r) * 128 + q * 8];
  }
  __syncthreads();

  f32x4 acc[4];
  #pragma unroll
  for (int t = 0; t < 4; ++t) acc[t] = (f32x4){0.f, 0.f, 0.f, 0.f};

  #pragma unroll
  for (int s = 0; s < 4; ++s) {
    #pragma unroll
    for (int t = 0; t < 4; ++t) {
      s16x8 bh = *(const s16x8*)&Bh[(t * 16 + ln) * 136 + s * 32 + quad * 8];
      s16x8 bl = *(const s16x8*)&Bl[(t * 16 + ln) * 136 + s * 32 + quad * 8];
      acc[t] = __builtin_amdgcn_mfma_f32_16x16x32_bf16(ah[s], bh, acc[t], 0, 0, 0);
      acc[t] = __builtin_amdgcn_mfma_f32_16x16x32_bf16(al[s], bh, acc[t], 0, 0, 0);
      acc[t] = __builtin_amdgcn_mfma_f32_16x16x32_bf16(ah[s], bl, acc[t], 0, 0, 0);
    }
  }

  int brow = b0 + w * 16 + quad * 4;
  #pragma unroll
  for (int t = 0; t < 4; ++t) {
    int ncol = n0 + t * 16 + ln;
    #pragma unroll
    for (int r = 0; r < 4; ++r) {
      outS[(size_t)(brow + r) * N_NODE + ncol] = acc[t][r];
    }
  }
}

// ---------------- per-row logsumexp + target score ----------------
__global__ __launch_bounds__(256) void klse(const float* __restrict__ outS,
                                            const int* __restrict__ tar,
                                            float* __restrict__ part) {
  __shared__ float ms[256], ss[256];
  int b = blockIdx.x, tid = threadIdx.x;
  const float2* sp = (const float2*)(outS + (size_t)b * N_NODE);
  float m = -INFINITY, s = 0.f;
  for (int i = tid; i < N_NODE / 2; i += 256) {
    float2 v = sp[i];
    float mx = fmaxf(v.x, v.y);
    float add = expf(v.x - mx) + expf(v.y - mx);
    if (mx > m) { s = s * expf(m - mx) + add; m = mx; }
    else s += add * expf(mx - m);
  }
  ms[tid] = m; ss[tid] = s;
  __syncthreads();
  for (int st = 128; st; st >>= 1) {
    if (tid < st) {
      float m2 = ms[tid + st], s2 = ss[tid + st];
      float M = fmaxf(ms[tid], m2);
      ss[tid] = ss[tid] * expf(ms[tid] - M) + s2 * expf(m2 - M);
      ms[tid] = M;
    }
    __syncthreads();
  }
  if (tid == 0) {
    float tsc = outS[(size_t)b * N_NODE + tar[b]];
    part[b] = tsc - (ms[0] + logf(ss[0]));
  }
}

__global__ void kfinal(const float* __restrict__ part, float* __restrict__ out) {
  __shared__ float red[256];
  int tid = threadIdx.x;
  red[tid] = part[tid] + part[tid + 256];
  __syncthreads();
  for (int st = 128; st; st >>= 1) {
    if (tid < st) red[tid] += red[tid + st];
    __syncthreads();
  }
  if (tid == 0) {
    out[0] = 0.f;                        // con_loss
    out[1] = -red[0] / (float)BB;        // loss
  }
}

extern "C" void kernel_launch(void* const* d_in, const int* in_sizes, int n_in,
                              void* d_out, int out_size, void* d_ws, size_t ws_size,
                              hipStream_t stream) {
  const int* tar    = (const int*)d_in[0];
  const int* rev    = (const int*)d_in[1];
  const int* maskp  = (const int*)d_in[2];
  const float* slen = (const float*)d_in[3];
  const float* sadj = (const float*)d_in[4];
  const int* items  = (const int*)d_in[6];
  const int* adjp   = (const int*)d_in[7];
  const int* alias  = (const int*)d_in[8];
  const int* grows  = (const int*)d_in[9];
  const int* gcols  = (const int*)d_in[10];
  const float* gvals = (const float*)d_in[11];
  const float* nemb = (const float*)d_in[12];
  const float* bI   = (const float*)d_in[13];
  const float* aS   = (const float*)d_in[14];
  const float* a0p  = (const float*)d_in[15];
  const float* a1p  = (const float*)d_in[16];
  const float* a2p  = (const float*)d_in[17];
  const float* a3p  = (const float*)d_in[18];
  const float* w1W  = (const float*)d_in[19];
  const float* w1b  = (const float*)d_in[20];
  const float* w2p  = (const float*)d_in[21];
  const float* g1W  = (const float*)d_in[22];
  const float* g1b  = (const float*)d_in[23];
  const float* g2W  = (const float*)d_in[24];
  const float* posE = (const float*)d_in[25];

  float* W = (float*)d_ws;
  size_t o = 0;
  float* emb_gnn = W + o; o += (size_t)N_NODE * EMB;   // 4,000,000
  float* x1      = W + o; o += (size_t)N_NODE * EMB;   // reused: hgat, then bHi
  float* x2      = W + o; o += (size_t)N_NODE * EMB;   // reused: hseq, then bLo
  float* sel     = W + o; o += (size_t)BB * EMB;
  float* y1      = W + o; o += (size_t)BB * EMB;
  float* y2      = W + o; o += (size_t)BB * EMB;
  float* seqh    = W + o; o += (size_t)BB * EMB;
  float* posW    = W + o; o += 5120;
  float* w1t2    = W + o; o += 10000;
  float* glu1t   = W + o; o += 10000;
  float* glu2t   = W + o; o += 10000;
  float* valS    = W + o; o += EDG;
  float* part    = W + o; o += 512;
  int* colS   = (int*)(W + o); o += EDG;
  int* counts = (int*)(W + o); o += N_NODE;
  int* starts = (int*)(W + o); o += N_NODE;
  int* cursor = (int*)(W + o); o += N_NODE;
  int* scantmp = (int*)(W + o); o += N_NODE;
  int* blocksums = (int*)(W + o); o += 256;
  unsigned short* aHi = (unsigned short*)(W + o); o += 32768;  // 512*128 bf16 = 32768 floats/2
  unsigned short* aLo = (unsigned short*)(W + o); o += 32768;
  // hgat/hseq alias x1/x2 (dead after kcomb); bHi/bLo alias x1/x2 (hgat dead after
  // kseq, hseq dead after ksoft; each needs 2.56M floats of the 4M region)
  float* hgat = x1;
  float* hseq = x2;
  unsigned short* bHi = (unsigned short*)x1;   // 5.12M u16 = 2.56M floats <= 4M
  unsigned short* bLo = (unsigned short*)x2;

  float* outF = (float*)d_out;
  float* outScores = outF + 2;

  hipMemsetAsync(counts, 0, N_NODE * sizeof(int), stream);
  khist<<<EDG / 256, 256, 0, stream>>>(grows, counts);
  kscan1<<<SCAN_BLOCKS, 256, 0, stream>>>(counts, scantmp, blocksums, N_NODE);
  kscan2<<<1, 256, 0, stream>>>(blocksums, SCAN_BLOCKS);
  kscan3<<<SCAN_BLOCKS, 256, 0, stream>>>(scantmp, blocksums, starts, cursor, N_NODE);
  kfill<<<EDG / 256, 256, 0, stream>>>(grows, gcols, gvals, cursor, colS, valS);
  kspmm<<<N_NODE / 4, 256, 0, stream>>>(starts, counts, colS, valS, nemb, x1);
  kspmm<<<N_NODE / 4, 256, 0, stream>>>(starts, counts, colS, valS, x1, x2);
  kcomb<<<N_NODE / 4, 256, 0, stream>>>(nemb, x1, x2, bI, emb_gnn);
  kgat<<<BB, 256, 0, stream>>>(emb_gnn, items, adjp, a0p, a1p, a2p, a3p, hgat);
  kseq<<<(BB * LL * EMB) / 256, 256, 0, stream>>>(emb_gnn, rev, alias, hgat, hseq);
  kprep_t<<<40, 256, 0, stream>>>(w1W, g1W, g2W, w1t2, glu1t, glu2t);
  kprep_pos<<<20, 256, 0, stream>>>(posE, w1W, w1b, posW);
  ksoft<<<BB, 256, 0, stream>>>(hseq, slen, maskp, posW, w1t2, glu1t, g1b, glu2t, w2p, sel);
  // hgat(x1) dead after kseq, hseq(x2) dead after ksoft -> safe to build bHi/bLo now
  kprepB<<<(N_NODE * 128) / 256, 256, 0, stream>>>(emb_gnn, bHi, bLo);
  ksess<<<BB, 128, 0, stream>>>(sadj, sel, y1);
  ksess<<<BB, 128, 0, stream>>>(sadj, y1, y2);
  ksesscomb<<<BB / 4, 256, 0, stream>>>(sel, y1, y2, aS, seqh);
  kprepA<<<(BB * 128) / 256, 256, 0, stream>>>(seqh, aHi, aLo);
  kscoresM<<<dim3(N_NODE / 64, BB / 64), 256, 0, stream>>>(aHi, aLo, bHi, bLo, outScores);
  klse<<<BB, 256, 0, stream>>>(outScores, tar, part);
  kfinal<<<1, 256, 0, stream>>>(part, outF);
}